// Round 6
// baseline (668.695 us; speedup 1.0000x reference)
//
#include <hip/hip_runtime.h>
#include <cstdint>
#include <cstddef>

// DecoderLayer on MI355X (gfx950). Inputs f32, output f32, bf16 MFMA compute.
// B=4 S=1024 D=1024 H=16 DK=64 HID=2048

#define DEV __device__ __forceinline__

typedef __bf16 bf16x8 __attribute__((ext_vector_type(8)));
typedef float f32x4 __attribute__((ext_vector_type(4)));

DEV float bf2f(uint16_t h) { return __builtin_bit_cast(float, (uint32_t)h << 16); }
DEV uint16_t f2bf(float f) {
  uint32_t u = __builtin_bit_cast(uint32_t, f);
  return (uint16_t)((u + 0x7fffu + ((u >> 16) & 1u)) >> 16);
}

DEV void gload16(const void* g, void* l) {
  __builtin_amdgcn_global_load_lds((const __attribute__((address_space(1))) void*)g,
                                   (__attribute__((address_space(3))) void*)l, 16, 0, 0);
}

// ---------------------------------------------------------------- prep
// One kernel: cvt x,y (f32->bf16) + transpose all 7 weights (f32 KxN -> bf16 NxK).
// Blocks 0..8191: cvt (4096 for x, 4096 for y). Blocks 8192..20479: transposes.
__global__ __launch_bounds__(256) void prep(
    const float* __restrict__ x, const float* __restrict__ y,
    uint16_t* __restrict__ xb, uint16_t* __restrict__ yb,
    const float* __restrict__ w0, uint16_t* __restrict__ t0,   // qkv 1024x3072
    const float* __restrict__ w1, uint16_t* __restrict__ t1,   // ao  1024x1024
    const float* __restrict__ w2, uint16_t* __restrict__ t2,   // kv  1024x2048
    const float* __restrict__ w3, uint16_t* __restrict__ t3,   // q   1024x1024
    const float* __restrict__ w4, uint16_t* __restrict__ t4,   // co  1024x1024
    const float* __restrict__ w5, uint16_t* __restrict__ t5,   // fc1 1024x2048
    const float* __restrict__ w6, uint16_t* __restrict__ t6) { // fc2 2048x1024
  int bid = blockIdx.x;
  const int tid = threadIdx.x;
  if (bid < 8192) {
    const float* src = (bid < 4096) ? x : y;
    uint16_t* dst = (bid < 4096) ? xb : yb;
    const int i = (bid & 4095) * 256 + tid;
    const float4 v = ((const float4*)src)[i];
    const uint32_t lo = (uint32_t)f2bf(v.x) | ((uint32_t)f2bf(v.y) << 16);
    const uint32_t hi = (uint32_t)f2bf(v.z) | ((uint32_t)f2bf(v.w) << 16);
    ((uint2*)dst)[i] = make_uint2(lo, hi);
    return;
  }
  bid -= 8192;
  const float* W; uint16_t* T; int K, N, tile;
  if (bid < 3072)       { W = w0; T = t0; K = 1024; N = 3072; tile = bid; }
  else if (bid < 4096)  { W = w1; T = t1; K = 1024; N = 1024; tile = bid - 3072; }
  else if (bid < 6144)  { W = w2; T = t2; K = 1024; N = 2048; tile = bid - 4096; }
  else if (bid < 7168)  { W = w3; T = t3; K = 1024; N = 1024; tile = bid - 6144; }
  else if (bid < 8192)  { W = w4; T = t4; K = 1024; N = 1024; tile = bid - 7168; }
  else if (bid < 10240) { W = w5; T = t5; K = 1024; N = 2048; tile = bid - 8192; }
  else                  { W = w6; T = t6; K = 2048; N = 1024; tile = bid - 10240; }
  const int ntx = N >> 5;
  const int n0 = (tile % ntx) * 32, k0 = (tile / ntx) * 32;
  __shared__ float t[32][33];
  const int tx = tid & 31, ty = tid >> 5;
#pragma unroll
  for (int i = 0; i < 32; i += 8)
    t[ty + i][tx] = W[(size_t)(k0 + ty + i) * N + n0 + tx];
  __syncthreads();
#pragma unroll
  for (int i = 0; i < 32; i += 8)
    T[(size_t)(n0 + ty + i) * K + k0 + tx] = f2bf(t[tx][ty + i]);
}

// ---------------------------------------------------------------- GEMM
// C[M][N] = A[M][K] @ W[K][N] + bias(f32), W pre-transposed as Bt[N][K] bf16.
// 128x128 tile, BK=32, 4 waves (2x2 of 64x64), mfma_f32_16x16x32_bf16.
enum { EP_QKV = 0, EP_RES_F32RES, EP_SCKV, EP_Q, EP_F32, EP_RELU, EP_RES_B16RES };

template <int EPI>
__global__ __launch_bounds__(256) void gemm_bt(const uint16_t* __restrict__ A,
                                               const uint16_t* __restrict__ Bt,
                                               const float* __restrict__ bias,
                                               void* __restrict__ out0,
                                               const void* __restrict__ res,
                                               int M, int N, int K) {
  __shared__ __align__(16) uint16_t As[128 * 32];
  __shared__ __align__(16) uint16_t Bs[128 * 32];
  const int tid = threadIdx.x;
  const int wid = tid >> 6, lane = tid & 63;
  const int g = lane >> 4, lr = lane & 15;
  const int wr = wid >> 1, wc = wid & 1;
  const int m0 = blockIdx.y * 128, n0 = blockIdx.x * 128;

  const char* Ab = (const char*)A;
  const char* Bb = (const char*)Bt;
  const size_t rs = (size_t)K * 2;

  // staging: 8 chunks of 1KB per tile (16 rows x 64B); wave w does chunks 2w,2w+1
  const int rc = lane >> 2;                                  // row within chunk
  const int scb = ((lane & 3) << 4) ^ ((rc & 3) << 4);       // swizzled src col byte

  // fragment read offsets (swizzle: byte ^= (row&3)<<4), per-lane constants
  int aoff[4], boff[4];
#pragma unroll
  for (int m = 0; m < 4; ++m) {
    const int row = wr * 64 + m * 16 + lr;
    aoff[m] = row * 64 + ((g * 16) ^ ((row & 3) << 4));
  }
#pragma unroll
  for (int n = 0; n < 4; ++n) {
    const int row = wc * 64 + n * 16 + lr;
    boff[n] = row * 64 + ((g * 16) ^ ((row & 3) << 4));
  }

  f32x4 acc[4][4] = {};
  const int nk = K >> 5;
  for (int kt = 0; kt < nk; ++kt) {
    __syncthreads();
#pragma unroll
    for (int i = 0; i < 2; ++i) {
      const int c = wid * 2 + i;
      gload16(Ab + (size_t)(m0 + c * 16 + rc) * rs + (size_t)kt * 64 + scb,
              (void*)((char*)As + c * 1024));
      gload16(Bb + (size_t)(n0 + c * 16 + rc) * rs + (size_t)kt * 64 + scb,
              (void*)((char*)Bs + c * 1024));
    }
    asm volatile("s_waitcnt vmcnt(0)" ::: "memory");
    __syncthreads();

    bf16x8 av[4], bv[4];
#pragma unroll
    for (int m = 0; m < 4; ++m) av[m] = *(const bf16x8*)((const char*)As + aoff[m]);
#pragma unroll
    for (int n = 0; n < 4; ++n) bv[n] = *(const bf16x8*)((const char*)Bs + boff[n]);
#pragma unroll
    for (int m = 0; m < 4; ++m)
#pragma unroll
      for (int n = 0; n < 4; ++n)
        acc[m][n] = __builtin_amdgcn_mfma_f32_16x16x32_bf16(av[m], bv[n], acc[m][n], 0, 0, 0);
  }

  // epilogue: C/D layout row=(lane>>4)*4+r, col=lane&15
#pragma unroll
  for (int m = 0; m < 4; ++m) {
#pragma unroll
    for (int n = 0; n < 4; ++n) {
      const int gcol = n0 + wc * 64 + n * 16 + lr;
      const float bb = bias[gcol];
#pragma unroll
      for (int r = 0; r < 4; ++r) {
        const int grow = m0 + wr * 64 + m * 16 + g * 4 + r;
        float v = acc[m][n][r] + bb;
        if constexpr (EPI == EP_QKV) {
          // qkv: per-head split AFTER _heads: h=n/192, part=(n%192)/64
          const int b = grow >> 10, s = grow & 1023;
          const int h = gcol / 192;
          const int rr = gcol - h * 192;
          const int part = rr >> 6, d = rr & 63;
          const int bh = b * 16 + h;
          uint16_t* base = (uint16_t*)out0;
          if (part == 2)
            base[2u * 4194304u + ((size_t)bh * 64 + d) * 1024 + s] = f2bf(v);  // Vt[bh][d][s]
          else
            base[(size_t)part * 4194304u + ((size_t)bh * 1024 + s) * 64 + d] = f2bf(v);
        } else if constexpr (EPI == EP_SCKV) {
          // kv: h=n>>7, part=(n>>6)&1 (ck then cv)
          const int b = grow >> 10, s = grow & 1023;
          const int h = gcol >> 7, part = (gcol >> 6) & 1, d = gcol & 63;
          const int bh = b * 16 + h;
          uint16_t* base = (uint16_t*)out0;  // CK; CVt = base + 4194304
          if (part == 0)
            base[((size_t)bh * 1024 + s) * 64 + d] = f2bf(v);
          else
            base[4194304u + ((size_t)bh * 64 + d) * 1024 + s] = f2bf(v);
        } else if constexpr (EPI == EP_Q) {
          const int b = grow >> 10, s = grow & 1023;
          const int h = gcol >> 6, d = gcol & 63;
          ((uint16_t*)out0)[((size_t)(b * 16 + h) * 1024 + s) * 64 + d] = f2bf(v);
        } else if constexpr (EPI == EP_RES_F32RES) {
          v += ((const float*)res)[(size_t)grow * N + gcol];
          ((float*)out0)[(size_t)grow * N + gcol] = v;
        } else if constexpr (EPI == EP_F32) {
          ((float*)out0)[(size_t)grow * N + gcol] = v;
        } else if constexpr (EPI == EP_RELU) {
          ((uint16_t*)out0)[(size_t)grow * N + gcol] = f2bf(v > 0.f ? v : 0.f);
        } else if constexpr (EPI == EP_RES_B16RES) {
          v += bf2f(((const uint16_t*)res)[(size_t)grow * N + gcol]);
          ((float*)out0)[(size_t)grow * N + gcol] = v;
        }
      }
    }
  }
}

// ---------------------------------------------------------------- attention
// Fused flash attention, barrier-free: K/V fragments read directly from global
// (K/V tiles are L1/L2-resident: 128KB per bh, shared by 16 q-blocks).
// Q,K: [BH][S][64] bf16; Vt: [BH][64][S] bf16. O merged: [B][S][H*64] bf16.
// grid(S/64, B*H), 4 independent waves x 16 q-rows; only P uses (wave-private) LDS.
template <bool CAUSAL>
__global__ __launch_bounds__(256) void attn_fused(const uint16_t* __restrict__ Qp,
                                                  const uint16_t* __restrict__ Kp,
                                                  const uint16_t* __restrict__ Vtp,
                                                  uint16_t* __restrict__ O) {
  __shared__ __align__(16) uint16_t Pl[4][16 * 64];
  const int tid = threadIdx.x, wid = tid >> 6, lane = tid & 63;
  const int g = lane >> 4, lr = lane & 15;
  const int qb = blockIdx.x, bh = blockIdx.y;
  const char* Qb = (const char*)(Qp + (size_t)bh * 65536);
  const char* Kb = (const char*)(Kp + (size_t)bh * 65536);
  const char* Vb = (const char*)(Vtp + (size_t)bh * 65536);
  const int q0 = qb * 64 + wid * 16;

  bf16x8 aq[2];
#pragma unroll
  for (int ks = 0; ks < 2; ++ks)
    aq[ks] = *(const bf16x8*)(Qb + ((size_t)(q0 + lr) * 64 + ks * 32 + g * 8) * 2);

  float m_run[4], l_run[4];
  f32x4 oacc[4] = {};
#pragma unroll
  for (int r = 0; r < 4; ++r) { m_run[r] = -1e30f; l_run[r] = 0.f; }

  const int nkt = CAUSAL ? (qb + 1) : 16;
  char* Pb = (char*)Pl[wid];

  for (int kt = 0; kt < nkt; ++kt) {
    // diagonal tile: n-blocks entirely above the diagonal carry no data
    const int nlim = (CAUSAL && kt == qb) ? wid : 3;

    // K fragments direct from global: row s = kt*64+n*16+lr, col d = ks*32+g*8
    bf16x8 bk[4][2];
#pragma unroll
    for (int n = 0; n < 4; ++n)
      if (n <= nlim)
#pragma unroll
        for (int ks = 0; ks < 2; ++ks)
          bk[n][ks] = *(const bf16x8*)(Kb + ((size_t)(kt * 64 + n * 16 + lr) * 64 + ks * 32 + g * 8) * 2);

    f32x4 sc[4];
#pragma unroll
    for (int n = 0; n < 4; ++n) {
      if (n <= nlim) {
        f32x4 t = {};
#pragma unroll
        for (int ks = 0; ks < 2; ++ks)
          t = __builtin_amdgcn_mfma_f32_16x16x32_bf16(aq[ks], bk[n][ks], t, 0, 0, 0);
        sc[n] = t;
      } else {
        sc[n] = f32x4{-1e10f, -1e10f, -1e10f, -1e10f};
      }
    }

    float p[4][4];
#pragma unroll
    for (int n = 0; n < 4; ++n)
#pragma unroll
      for (int r = 0; r < 4; ++r) {
        float v = sc[n][r] * 0.125f;
        if (CAUSAL) {
          const int k_abs = kt * 64 + n * 16 + lr;
          const int q_abs = q0 + g * 4 + r;
          if (k_abs > q_abs) v = -1e9f;
        }
        p[n][r] = v;
      }
    // online softmax per q-row (row data lives in 16-lane group, 4 cols/lane)
#pragma unroll
    for (int r = 0; r < 4; ++r) {
      float mx = fmaxf(fmaxf(p[0][r], p[1][r]), fmaxf(p[2][r], p[3][r]));
      mx = fmaxf(mx, __shfl_xor(mx, 1));
      mx = fmaxf(mx, __shfl_xor(mx, 2));
      mx = fmaxf(mx, __shfl_xor(mx, 4));
      mx = fmaxf(mx, __shfl_xor(mx, 8));
      const float mnew = fmaxf(m_run[r], mx);
      const float f = __expf(m_run[r] - mnew);
      m_run[r] = mnew;
      float ls = 0.f;
#pragma unroll
      for (int n = 0; n < 4; ++n) {
        const float e = __expf(p[n][r] - mnew);
        p[n][r] = e;
        ls += e;
      }
      ls += __shfl_xor(ls, 1);
      ls += __shfl_xor(ls, 2);
      ls += __shfl_xor(ls, 4);
      ls += __shfl_xor(ls, 8);
      l_run[r] = l_run[r] * f + ls;
#pragma unroll
      for (int n = 0; n < 4; ++n) oacc[n][r] *= f;
    }
    // P -> wave-private LDS (bf16, swizzled), then reload as A-fragments
#pragma unroll
    for (int n = 0; n < 4; ++n)
#pragma unroll
      for (int r = 0; r < 4; ++r) {
        const int row = g * 4 + r;
        *(uint16_t*)(Pb + row * 128 + ((n * 32 + lr * 2) ^ ((row & 7) << 4))) = f2bf(p[n][r]);
      }
    asm volatile("s_waitcnt lgkmcnt(0)" ::: "memory");
#pragma unroll
    for (int ks = 0; ks < 2; ++ks) {
      bf16x8 pa = *(const bf16x8*)(Pb + lr * 128 + ((ks * 64 + g * 16) ^ ((lr & 7) << 4)));
#pragma unroll
      for (int n2 = 0; n2 < 4; ++n2) {
        // V fragment direct from global: row d = n2*16+lr, col s = kt*64+ks*32+g*8
        bf16x8 bv = *(const bf16x8*)(Vb + ((size_t)(n2 * 16 + lr) * 1024 + kt * 64 + ks * 32 + g * 8) * 2);
        oacc[n2] = __builtin_amdgcn_mfma_f32_16x16x32_bf16(pa, bv, oacc[n2], 0, 0, 0);
      }
    }
  }

  const int b = bh >> 4, h = bh & 15;
#pragma unroll
  for (int n2 = 0; n2 < 4; ++n2)
#pragma unroll
    for (int r = 0; r < 4; ++r) {
      const int q = q0 + g * 4 + r, d = n2 * 16 + lr;
      const float v = oacc[n2][r] / l_run[r];
      O[(size_t)(b * 1024 + q) * 1024 + h * 64 + d] = f2bf(v);
    }
}

// ---------------------------------------------------------------- layernorm
// One 256-thread block per row (D=1024). fp32 in; optional post-add; f32/bf16 out.
__global__ __launch_bounds__(256) void ln_kernel(const float* __restrict__ in,
                                                 const float* __restrict__ gam,
                                                 const float* __restrict__ bet,
                                                 const float* __restrict__ addend,
                                                 float* __restrict__ outf,
                                                 uint16_t* __restrict__ outb) {
  __shared__ float red[4];
  const int tid = threadIdx.x;
  const size_t row = blockIdx.x;
  const float4 v = ((const float4*)(in + row * 1024))[tid];
  float s = v.x + v.y + v.z + v.w;
#pragma unroll
  for (int o = 1; o < 64; o <<= 1) s += __shfl_xor(s, o);
  const int wid = tid >> 6, lane = tid & 63;
  if (lane == 0) red[wid] = s;
  __syncthreads();
  s = red[0] + red[1] + red[2] + red[3];
  const float mu = s * (1.f / 1024.f);
  const float d0 = v.x - mu, d1 = v.y - mu, d2 = v.z - mu, d3 = v.w - mu;
  float sq = d0 * d0 + d1 * d1 + d2 * d2 + d3 * d3;
  __syncthreads();
#pragma unroll
  for (int o = 1; o < 64; o <<= 1) sq += __shfl_xor(sq, o);
  if (lane == 0) red[wid] = sq;
  __syncthreads();
  sq = red[0] + red[1] + red[2] + red[3];
  const float inv = rsqrtf(sq * (1.f / 1024.f) + 1e-5f);
  const float4 gv = ((const float4*)(gam))[tid];
  const float4 bv = ((const float4*)(bet))[tid];
  float o0 = d0 * inv * gv.x + bv.x;
  float o1 = d1 * inv * gv.y + bv.y;
  float o2 = d2 * inv * gv.z + bv.z;
  float o3 = d3 * inv * gv.w + bv.w;
  if (addend) {
    const float4 a = ((const float4*)(addend + row * 1024))[tid];
    o0 += a.x; o1 += a.y; o2 += a.z; o3 += a.w;
  }
  if (outf)
    ((float4*)(outf + row * 1024))[tid] = make_float4(o0, o1, o2, o3);
  if (outb) {
    const uint32_t w0 = (uint32_t)f2bf(o0) | ((uint32_t)f2bf(o1) << 16);
    const uint32_t w1 = (uint32_t)f2bf(o2) | ((uint32_t)f2bf(o3) << 16);
    ((uint2*)(outb + row * 1024))[tid] = make_uint2(w0, w1);
  }
}

// ---------------------------------------------------------------- launch
extern "C" void kernel_launch(void* const* d_in, const int* in_sizes, int n_in,
                              void* d_out, int out_size, void* d_ws, size_t ws_size,
                              hipStream_t stream) {
  (void)in_sizes; (void)n_in; (void)out_size; (void)ws_size;
  const float* x     = (const float*)d_in[0];
  const float* y     = (const float*)d_in[1];
  const float* qkv_w = (const float*)d_in[3];
  const float* qkv_b = (const float*)d_in[4];
  const float* ao_w  = (const float*)d_in[5];
  const float* ao_b  = (const float*)d_in[6];
  const float* kv_w  = (const float*)d_in[7];
  const float* kv_b  = (const float*)d_in[8];
  const float* q_w   = (const float*)d_in[9];
  const float* q_b   = (const float*)d_in[10];
  const float* co_w  = (const float*)d_in[11];
  const float* co_b  = (const float*)d_in[12];
  const float* fc1_w = (const float*)d_in[13];
  const float* fc1_b = (const float*)d_in[14];
  const float* fc2_w = (const float*)d_in[15];
  const float* fc2_b = (const float*)d_in[16];
  const float* ln1_g = (const float*)d_in[17];
  const float* ln1_b = (const float*)d_in[18];
  const float* ln2_g = (const float*)d_in[19];
  const float* ln2_b = (const float*)d_in[20];
  const float* ln3_g = (const float*)d_in[21];
  const float* ln3_b = (const float*)d_in[22];

  char* ws = (char*)d_ws;
  size_t off = 0;
  auto alloc = [&](size_t bytes) {
    char* p = ws + off;
    off += (bytes + 255) & ~(size_t)255;
    return p;
  };
  uint16_t* xb     = (uint16_t*)alloc(4194304ull * 2);      // x bf16
  uint16_t* yb     = (uint16_t*)alloc(4194304ull * 2);      // y bf16
  uint16_t* wT_qkv = (uint16_t*)alloc(3072ull * 1024 * 2);
  uint16_t* wT_ao  = (uint16_t*)alloc(1024ull * 1024 * 2);
  uint16_t* wT_kv  = (uint16_t*)alloc(2048ull * 1024 * 2);
  uint16_t* wT_q   = (uint16_t*)alloc(1024ull * 1024 * 2);
  uint16_t* wT_co  = (uint16_t*)alloc(1024ull * 1024 * 2);
  uint16_t* wT_fc1 = (uint16_t*)alloc(2048ull * 1024 * 2);
  uint16_t* wT_fc2 = (uint16_t*)alloc(1024ull * 2048 * 2);
  uint16_t* QKV    = (uint16_t*)alloc(3ull * 4194304 * 2);  // Q|K|Vt, reused as CQ|CK|CVt
  uint16_t* SA     = (uint16_t*)alloc(4194304ull * 2);      // attn out merged (both attns)
  float*    YATT   = (float*)alloc(4194304ull * 4);         // y_att f32; later F1 (bf16)
  float*    TMP    = (float*)alloc(4194304ull * 4);         // pre-LN f32, reused 3x
  uint16_t* YCB    = (uint16_t*)alloc(4194304ull * 2);      // y_cross bf16

  const dim3 blk(256);

  prep<<<dim3(20480), blk, 0, stream>>>(x, y, xb, yb,
                                        qkv_w, wT_qkv, ao_w, wT_ao, kv_w, wT_kv,
                                        q_w, wT_q, co_w, wT_co, fc1_w, wT_fc1, fc2_w, wT_fc2);

  // self-attention branch
  gemm_bt<EP_QKV><<<dim3(24, 32), blk, 0, stream>>>(yb, wT_qkv, qkv_b, QKV, nullptr, 4096, 3072, 1024);
  attn_fused<true><<<dim3(16, 64), blk, 0, stream>>>(QKV, QKV + 4194304, QKV + 2 * 4194304, SA);
  gemm_bt<EP_RES_F32RES><<<dim3(8, 32), blk, 0, stream>>>(SA, wT_ao, ao_b, TMP, y, 4096, 1024, 1024);
  ln_kernel<<<dim3(4096), blk, 0, stream>>>(TMP, ln1_g, ln1_b, nullptr, YATT, nullptr);
  // cross-attention branch (kv from x, q from original y)
  gemm_bt<EP_SCKV><<<dim3(16, 32), blk, 0, stream>>>(xb, wT_kv, kv_b, QKV + 4194304, nullptr, 4096, 2048, 1024);
  gemm_bt<EP_Q><<<dim3(8, 32), blk, 0, stream>>>(yb, wT_q, q_b, QKV, nullptr, 4096, 1024, 1024);
  attn_fused<false><<<dim3(16, 64), blk, 0, stream>>>(QKV, QKV + 4194304, QKV + 2 * 4194304, SA);
  gemm_bt<EP_F32><<<dim3(8, 32), blk, 0, stream>>>(SA, wT_co, co_b, TMP, nullptr, 4096, 1024, 1024);
  ln_kernel<<<dim3(4096), blk, 0, stream>>>(TMP, ln2_g, ln2_b, YATT, nullptr, YCB);
  // feedforward
  gemm_bt<EP_RELU><<<dim3(16, 32), blk, 0, stream>>>(YCB, wT_fc1, fc1_b, (uint16_t*)YATT, nullptr, 4096, 2048, 1024);
  gemm_bt<EP_RES_B16RES><<<dim3(8, 32), blk, 0, stream>>>((const uint16_t*)YATT, wT_fc2, fc2_b, TMP, YCB, 4096, 1024, 2048);
  ln_kernel<<<dim3(4096), blk, 0, stream>>>(TMP, ln3_g, ln3_b, nullptr, (float*)d_out, nullptr);
}

// Round 7
// 542.380 us; speedup vs baseline: 1.2329x; 1.2329x over previous
//
#include <hip/hip_runtime.h>
#include <cstdint>
#include <cstddef>

// DecoderLayer on MI355X (gfx950). Inputs f32, output f32, bf16 MFMA compute.
// B=4 S=1024 D=1024 H=16 DK=64 HID=2048

#define DEV __device__ __forceinline__

typedef __bf16 bf16x8 __attribute__((ext_vector_type(8)));
typedef float f32x4 __attribute__((ext_vector_type(4)));

DEV float bf2f(uint16_t h) { return __builtin_bit_cast(float, (uint32_t)h << 16); }
DEV uint16_t f2bf(float f) {
  uint32_t u = __builtin_bit_cast(uint32_t, f);
  return (uint16_t)((u + 0x7fffu + ((u >> 16) & 1u)) >> 16);
}

DEV void gload16(const void* g, void* l) {
  __builtin_amdgcn_global_load_lds((const __attribute__((address_space(1))) void*)g,
                                   (__attribute__((address_space(3))) void*)l, 16, 0, 0);
}

// ---------------------------------------------------------------- prep
// One kernel: cvt x,y (f32->bf16) + transpose all 7 weights (f32 KxN -> bf16 NxK).
// Blocks 0..8191: cvt (4096 for x, 4096 for y). Blocks 8192..20479: transposes.
__global__ __launch_bounds__(256) void prep(
    const float* __restrict__ x, const float* __restrict__ y,
    uint16_t* __restrict__ xb, uint16_t* __restrict__ yb,
    const float* __restrict__ w0, uint16_t* __restrict__ t0,   // qkv 1024x3072
    const float* __restrict__ w1, uint16_t* __restrict__ t1,   // ao  1024x1024
    const float* __restrict__ w2, uint16_t* __restrict__ t2,   // kv  1024x2048
    const float* __restrict__ w3, uint16_t* __restrict__ t3,   // q   1024x1024
    const float* __restrict__ w4, uint16_t* __restrict__ t4,   // co  1024x1024
    const float* __restrict__ w5, uint16_t* __restrict__ t5,   // fc1 1024x2048
    const float* __restrict__ w6, uint16_t* __restrict__ t6) { // fc2 2048x1024
  int bid = blockIdx.x;
  const int tid = threadIdx.x;
  if (bid < 8192) {
    const float* src = (bid < 4096) ? x : y;
    uint16_t* dst = (bid < 4096) ? xb : yb;
    const int i = (bid & 4095) * 256 + tid;
    const float4 v = ((const float4*)src)[i];
    const uint32_t lo = (uint32_t)f2bf(v.x) | ((uint32_t)f2bf(v.y) << 16);
    const uint32_t hi = (uint32_t)f2bf(v.z) | ((uint32_t)f2bf(v.w) << 16);
    ((uint2*)dst)[i] = make_uint2(lo, hi);
    return;
  }
  bid -= 8192;
  const float* W; uint16_t* T; int K, N, tile;
  if (bid < 3072)       { W = w0; T = t0; K = 1024; N = 3072; tile = bid; }
  else if (bid < 4096)  { W = w1; T = t1; K = 1024; N = 1024; tile = bid - 3072; }
  else if (bid < 6144)  { W = w2; T = t2; K = 1024; N = 2048; tile = bid - 4096; }
  else if (bid < 7168)  { W = w3; T = t3; K = 1024; N = 1024; tile = bid - 6144; }
  else if (bid < 8192)  { W = w4; T = t4; K = 1024; N = 1024; tile = bid - 7168; }
  else if (bid < 10240) { W = w5; T = t5; K = 1024; N = 2048; tile = bid - 8192; }
  else                  { W = w6; T = t6; K = 2048; N = 1024; tile = bid - 10240; }
  const int ntx = N >> 5;
  const int n0 = (tile % ntx) * 32, k0 = (tile / ntx) * 32;
  __shared__ float t[32][33];
  const int tx = tid & 31, ty = tid >> 5;
#pragma unroll
  for (int i = 0; i < 32; i += 8)
    t[ty + i][tx] = W[(size_t)(k0 + ty + i) * N + n0 + tx];
  __syncthreads();
#pragma unroll
  for (int i = 0; i < 32; i += 8)
    T[(size_t)(n0 + ty + i) * K + k0 + tx] = f2bf(t[tx][ty + i]);
}

// ---------------------------------------------------------------- GEMM
// C[M][N] = A[M][K] @ W[K][N] + bias(f32), W pre-transposed as Bt[N][K] bf16.
// 128x128 tile, BK=32, 4 waves (2x2 of 64x64), mfma_f32_16x16x32_bf16.
enum { EP_QKV = 0, EP_RES_F32RES, EP_SCKV, EP_Q, EP_F32, EP_RELU, EP_RES_B16RES };

template <int EPI>
__global__ __launch_bounds__(256) void gemm_bt(const uint16_t* __restrict__ A,
                                               const uint16_t* __restrict__ Bt,
                                               const float* __restrict__ bias,
                                               void* __restrict__ out0,
                                               const void* __restrict__ res,
                                               int M, int N, int K) {
  __shared__ __align__(16) uint16_t As[128 * 32];
  __shared__ __align__(16) uint16_t Bs[128 * 32];
  const int tid = threadIdx.x;
  const int wid = tid >> 6, lane = tid & 63;
  const int g = lane >> 4, lr = lane & 15;
  const int wr = wid >> 1, wc = wid & 1;
  const int m0 = blockIdx.y * 128, n0 = blockIdx.x * 128;

  const char* Ab = (const char*)A;
  const char* Bb = (const char*)Bt;
  const size_t rs = (size_t)K * 2;

  // staging: 8 chunks of 1KB per tile (16 rows x 64B); wave w does chunks 2w,2w+1
  const int rc = lane >> 2;                                  // row within chunk
  const int scb = ((lane & 3) << 4) ^ ((rc & 3) << 4);       // swizzled src col byte

  // fragment read offsets (swizzle: byte ^= (row&3)<<4), per-lane constants
  int aoff[4], boff[4];
#pragma unroll
  for (int m = 0; m < 4; ++m) {
    const int row = wr * 64 + m * 16 + lr;
    aoff[m] = row * 64 + ((g * 16) ^ ((row & 3) << 4));
  }
#pragma unroll
  for (int n = 0; n < 4; ++n) {
    const int row = wc * 64 + n * 16 + lr;
    boff[n] = row * 64 + ((g * 16) ^ ((row & 3) << 4));
  }

  f32x4 acc[4][4] = {};
  const int nk = K >> 5;
  for (int kt = 0; kt < nk; ++kt) {
    __syncthreads();
#pragma unroll
    for (int i = 0; i < 2; ++i) {
      const int c = wid * 2 + i;
      gload16(Ab + (size_t)(m0 + c * 16 + rc) * rs + (size_t)kt * 64 + scb,
              (void*)((char*)As + c * 1024));
      gload16(Bb + (size_t)(n0 + c * 16 + rc) * rs + (size_t)kt * 64 + scb,
              (void*)((char*)Bs + c * 1024));
    }
    asm volatile("s_waitcnt vmcnt(0)" ::: "memory");
    __syncthreads();

    bf16x8 av[4], bv[4];
#pragma unroll
    for (int m = 0; m < 4; ++m) av[m] = *(const bf16x8*)((const char*)As + aoff[m]);
#pragma unroll
    for (int n = 0; n < 4; ++n) bv[n] = *(const bf16x8*)((const char*)Bs + boff[n]);
#pragma unroll
    for (int m = 0; m < 4; ++m)
#pragma unroll
      for (int n = 0; n < 4; ++n)
        acc[m][n] = __builtin_amdgcn_mfma_f32_16x16x32_bf16(av[m], bv[n], acc[m][n], 0, 0, 0);
  }

  // epilogue: C/D layout row=(lane>>4)*4+r, col=lane&15
#pragma unroll
  for (int m = 0; m < 4; ++m) {
#pragma unroll
    for (int n = 0; n < 4; ++n) {
      const int gcol = n0 + wc * 64 + n * 16 + lr;
      const float bb = bias[gcol];
#pragma unroll
      for (int r = 0; r < 4; ++r) {
        const int grow = m0 + wr * 64 + m * 16 + g * 4 + r;
        float v = acc[m][n][r] + bb;
        if constexpr (EPI == EP_QKV) {
          // qkv: per-head split AFTER _heads: h=n/192, part=(n%192)/64
          const int b = grow >> 10, s = grow & 1023;
          const int h = gcol / 192;
          const int rr = gcol - h * 192;
          const int part = rr >> 6, d = rr & 63;
          const int bh = b * 16 + h;
          uint16_t* base = (uint16_t*)out0;
          if (part == 2)
            base[2u * 4194304u + ((size_t)bh * 64 + d) * 1024 + s] = f2bf(v);  // Vt[bh][d][s]
          else
            base[(size_t)part * 4194304u + ((size_t)bh * 1024 + s) * 64 + d] = f2bf(v);
        } else if constexpr (EPI == EP_SCKV) {
          // kv: h=n>>7, part=(n>>6)&1 (ck then cv)
          const int b = grow >> 10, s = grow & 1023;
          const int h = gcol >> 7, part = (gcol >> 6) & 1, d = gcol & 63;
          const int bh = b * 16 + h;
          uint16_t* base = (uint16_t*)out0;  // CK; CVt = base + 4194304
          if (part == 0)
            base[((size_t)bh * 1024 + s) * 64 + d] = f2bf(v);
          else
            base[4194304u + ((size_t)bh * 64 + d) * 1024 + s] = f2bf(v);
        } else if constexpr (EPI == EP_Q) {
          const int b = grow >> 10, s = grow & 1023;
          const int h = gcol >> 6, d = gcol & 63;
          ((uint16_t*)out0)[((size_t)(b * 16 + h) * 1024 + s) * 64 + d] = f2bf(v);
        } else if constexpr (EPI == EP_RES_F32RES) {
          v += ((const float*)res)[(size_t)grow * N + gcol];
          ((float*)out0)[(size_t)grow * N + gcol] = v;
        } else if constexpr (EPI == EP_F32) {
          ((float*)out0)[(size_t)grow * N + gcol] = v;
        } else if constexpr (EPI == EP_RELU) {
          ((uint16_t*)out0)[(size_t)grow * N + gcol] = f2bf(v > 0.f ? v : 0.f);
        } else if constexpr (EPI == EP_RES_B16RES) {
          v += bf2f(((const uint16_t*)res)[(size_t)grow * N + gcol]);
          ((float*)out0)[(size_t)grow * N + gcol] = v;
        }
      }
    }
  }
}

// ---------------------------------------------------------------- attention
// Fused flash attention, double-buffered LDS staging (2-phase pipeline):
// stage(kt+1) -> compute(kt) -> vmcnt(0)+barrier. K/V staged via global_load_lds
// (each byte loaded once per block, shared by 4 waves); loads for the next tile
// overlap the current tile's QK/softmax/PV compute.
// Q,K: [BH][S][64] bf16; Vt: [BH][64][S] bf16. O merged: [B][S][H*64] bf16.
// grid(S/64, B*H), 4 waves x 16 q-rows. LDS: 2x8K K + 2x8K V + 8K P = 40KB.
template <bool CAUSAL>
__global__ __launch_bounds__(256) void attn_fused(const uint16_t* __restrict__ Qp,
                                                  const uint16_t* __restrict__ Kp,
                                                  const uint16_t* __restrict__ Vtp,
                                                  uint16_t* __restrict__ O) {
  __shared__ __align__(16) uint16_t Kl[2][64 * 64];
  __shared__ __align__(16) uint16_t Vl[2][64 * 64];
  __shared__ __align__(16) uint16_t Pl[4][16 * 64];
  const int tid = threadIdx.x, wid = tid >> 6, lane = tid & 63;
  const int g = lane >> 4, lr = lane & 15;
  const int qb = blockIdx.x, bh = blockIdx.y;
  const char* Qb = (const char*)(Qp + (size_t)bh * 65536);
  const char* Kb = (const char*)(Kp + (size_t)bh * 65536);
  const char* Vb = (const char*)(Vtp + (size_t)bh * 65536);
  const int q0 = qb * 64 + wid * 16;

  bf16x8 aq[2];
#pragma unroll
  for (int ks = 0; ks < 2; ++ks)
    aq[ks] = *(const bf16x8*)(Qb + ((size_t)(q0 + lr) * 64 + ks * 32 + g * 8) * 2);

  float m_run[4], l_run[4];
  f32x4 oacc[4] = {};
#pragma unroll
  for (int r = 0; r < 4; ++r) { m_run[r] = -1e30f; l_run[r] = 0.f; }

  const int rc = lane >> 3;                             // row within 8-row chunk
  const int scb = ((lane & 7) << 4) ^ (rc << 4);        // swizzled src col byte
  const int nkt = CAUSAL ? (qb + 1) : 16;
  char* Pb = (char*)Pl[wid];

  // stage tile kt into buffer bufi: 8 chunks of 1KB each for K and V (2/wave)
  auto stage = [&](int kt, int bufi) {
#pragma unroll
    for (int i = 0; i < 2; ++i) {
      const int c = wid * 2 + i;
      gload16(Kb + (size_t)(kt * 64 + c * 8 + rc) * 128 + scb,
              (void*)((char*)Kl[bufi] + c * 1024));
      gload16(Vb + (size_t)(c * 8 + rc) * 2048 + kt * 128 + scb,
              (void*)((char*)Vl[bufi] + c * 1024));
    }
  };

  stage(0, 0);
  asm volatile("s_waitcnt vmcnt(0)" ::: "memory");
  __syncthreads();

  for (int kt = 0; kt < nkt; ++kt) {
    const int cur = kt & 1;
    if (kt + 1 < nkt) stage(kt + 1, cur ^ 1);   // prefetch overlaps this tile's compute
    const char* Kc = (const char*)Kl[cur];
    const char* Vc = (const char*)Vl[cur];
    // diagonal tile: n-blocks entirely above the diagonal carry no data
    const int nlim = (CAUSAL && kt == qb) ? wid : 3;

    // S = Q K^T * 0.125 (+causal mask)
    f32x4 sc[4];
#pragma unroll
    for (int n = 0; n < 4; ++n) {
      if (n <= nlim) {
        f32x4 t = {};
#pragma unroll
        for (int ks = 0; ks < 2; ++ks) {
          const int row = n * 16 + lr;
          bf16x8 bk = *(const bf16x8*)(Kc + row * 128 + ((ks * 64 + g * 16) ^ ((row & 7) << 4)));
          t = __builtin_amdgcn_mfma_f32_16x16x32_bf16(aq[ks], bk, t, 0, 0, 0);
        }
        sc[n] = t;
      } else {
        sc[n] = f32x4{-1e10f, -1e10f, -1e10f, -1e10f};
      }
    }

    float p[4][4];
#pragma unroll
    for (int n = 0; n < 4; ++n)
#pragma unroll
      for (int r = 0; r < 4; ++r) {
        float v = sc[n][r] * 0.125f;
        if (CAUSAL) {
          const int k_abs = kt * 64 + n * 16 + lr;
          const int q_abs = q0 + g * 4 + r;
          if (k_abs > q_abs) v = -1e9f;
        }
        p[n][r] = v;
      }
    // online softmax per q-row (row data lives in 16-lane group, 4 cols/lane)
#pragma unroll
    for (int r = 0; r < 4; ++r) {
      float mx = fmaxf(fmaxf(p[0][r], p[1][r]), fmaxf(p[2][r], p[3][r]));
      mx = fmaxf(mx, __shfl_xor(mx, 1));
      mx = fmaxf(mx, __shfl_xor(mx, 2));
      mx = fmaxf(mx, __shfl_xor(mx, 4));
      mx = fmaxf(mx, __shfl_xor(mx, 8));
      const float mnew = fmaxf(m_run[r], mx);
      const float f = __expf(m_run[r] - mnew);
      m_run[r] = mnew;
      float ls = 0.f;
#pragma unroll
      for (int n = 0; n < 4; ++n) {
        const float e = __expf(p[n][r] - mnew);
        p[n][r] = e;
        ls += e;
      }
      ls += __shfl_xor(ls, 1);
      ls += __shfl_xor(ls, 2);
      ls += __shfl_xor(ls, 4);
      ls += __shfl_xor(ls, 8);
      l_run[r] = l_run[r] * f + ls;
#pragma unroll
      for (int n = 0; n < 4; ++n) oacc[n][r] *= f;
    }
    // P -> wave-private LDS (bf16, swizzled), then reload as A-fragments
#pragma unroll
    for (int n = 0; n < 4; ++n)
#pragma unroll
      for (int r = 0; r < 4; ++r) {
        const int row = g * 4 + r;
        *(uint16_t*)(Pb + row * 128 + ((n * 32 + lr * 2) ^ ((row & 7) << 4))) = f2bf(p[n][r]);
      }
    asm volatile("s_waitcnt lgkmcnt(0)" ::: "memory");
#pragma unroll
    for (int ks = 0; ks < 2; ++ks) {
      bf16x8 pa = *(const bf16x8*)(Pb + lr * 128 + ((ks * 64 + g * 16) ^ ((lr & 7) << 4)));
#pragma unroll
      for (int n2 = 0; n2 < 4; ++n2) {
        const int row = n2 * 16 + lr;
        bf16x8 bv = *(const bf16x8*)(Vc + row * 128 + ((ks * 64 + g * 16) ^ ((row & 7) << 4)));
        oacc[n2] = __builtin_amdgcn_mfma_f32_16x16x32_bf16(pa, bv, oacc[n2], 0, 0, 0);
      }
    }
    asm volatile("s_waitcnt vmcnt(0)" ::: "memory");  // next tile's stage has landed
    __syncthreads();
  }

  const int b = bh >> 4, h = bh & 15;
#pragma unroll
  for (int n2 = 0; n2 < 4; ++n2)
#pragma unroll
    for (int r = 0; r < 4; ++r) {
      const int q = q0 + g * 4 + r, d = n2 * 16 + lr;
      const float v = oacc[n2][r] / l_run[r];
      O[(size_t)(b * 1024 + q) * 1024 + h * 64 + d] = f2bf(v);
    }
}

// ---------------------------------------------------------------- layernorm
// One 256-thread block per row (D=1024). fp32 in; optional post-add; f32/bf16 out.
__global__ __launch_bounds__(256) void ln_kernel(const float* __restrict__ in,
                                                 const float* __restrict__ gam,
                                                 const float* __restrict__ bet,
                                                 const float* __restrict__ addend,
                                                 float* __restrict__ outf,
                                                 uint16_t* __restrict__ outb) {
  __shared__ float red[4];
  const int tid = threadIdx.x;
  const size_t row = blockIdx.x;
  const float4 v = ((const float4*)(in + row * 1024))[tid];
  float s = v.x + v.y + v.z + v.w;
#pragma unroll
  for (int o = 1; o < 64; o <<= 1) s += __shfl_xor(s, o);
  const int wid = tid >> 6, lane = tid & 63;
  if (lane == 0) red[wid] = s;
  __syncthreads();
  s = red[0] + red[1] + red[2] + red[3];
  const float mu = s * (1.f / 1024.f);
  const float d0 = v.x - mu, d1 = v.y - mu, d2 = v.z - mu, d3 = v.w - mu;
  float sq = d0 * d0 + d1 * d1 + d2 * d2 + d3 * d3;
  __syncthreads();
#pragma unroll
  for (int o = 1; o < 64; o <<= 1) sq += __shfl_xor(sq, o);
  if (lane == 0) red[wid] = sq;
  __syncthreads();
  sq = red[0] + red[1] + red[2] + red[3];
  const float inv = rsqrtf(sq * (1.f / 1024.f) + 1e-5f);
  const float4 gv = ((const float4*)(gam))[tid];
  const float4 bv = ((const float4*)(bet))[tid];
  float o0 = d0 * inv * gv.x + bv.x;
  float o1 = d1 * inv * gv.y + bv.y;
  float o2 = d2 * inv * gv.z + bv.z;
  float o3 = d3 * inv * gv.w + bv.w;
  if (addend) {
    const float4 a = ((const float4*)(addend + row * 1024))[tid];
    o0 += a.x; o1 += a.y; o2 += a.z; o3 += a.w;
  }
  if (outf)
    ((float4*)(outf + row * 1024))[tid] = make_float4(o0, o1, o2, o3);
  if (outb) {
    const uint32_t w0 = (uint32_t)f2bf(o0) | ((uint32_t)f2bf(o1) << 16);
    const uint32_t w1 = (uint32_t)f2bf(o2) | ((uint32_t)f2bf(o3) << 16);
    ((uint2*)(outb + row * 1024))[tid] = make_uint2(w0, w1);
  }
}

// ---------------------------------------------------------------- launch
extern "C" void kernel_launch(void* const* d_in, const int* in_sizes, int n_in,
                              void* d_out, int out_size, void* d_ws, size_t ws_size,
                              hipStream_t stream) {
  (void)in_sizes; (void)n_in; (void)out_size; (void)ws_size;
  const float* x     = (const float*)d_in[0];
  const float* y     = (const float*)d_in[1];
  const float* qkv_w = (const float*)d_in[3];
  const float* qkv_b = (const float*)d_in[4];
  const float* ao_w  = (const float*)d_in[5];
  const float* ao_b  = (const float*)d_in[6];
  const float* kv_w  = (const float*)d_in[7];
  const float* kv_b  = (const float*)d_in[8];
  const float* q_w   = (const float*)d_in[9];
  const float* q_b   = (const float*)d_in[10];
  const float* co_w  = (const float*)d_in[11];
  const float* co_b  = (const float*)d_in[12];
  const float* fc1_w = (const float*)d_in[13];
  const float* fc1_b = (const float*)d_in[14];
  const float* fc2_w = (const float*)d_in[15];
  const float* fc2_b = (const float*)d_in[16];
  const float* ln1_g = (const float*)d_in[17];
  const float* ln1_b = (const float*)d_in[18];
  const float* ln2_g = (const float*)d_in[19];
  const float* ln2_b = (const float*)d_in[20];
  const float* ln3_g = (const float*)d_in[21];
  const float* ln3_b = (const float*)d_in[22];

  char* ws = (char*)d_ws;
  size_t off = 0;
  auto alloc = [&](size_t bytes) {
    char* p = ws + off;
    off += (bytes + 255) & ~(size_t)255;
    return p;
  };
  uint16_t* xb     = (uint16_t*)alloc(4194304ull * 2);      // x bf16
  uint16_t* yb     = (uint16_t*)alloc(4194304ull * 2);      // y bf16
  uint16_t* wT_qkv = (uint16_t*)alloc(3072ull * 1024 * 2);
  uint16_t* wT_ao  = (uint16_t*)alloc(1024ull * 1024 * 2);
  uint16_t* wT_kv  = (uint16_t*)alloc(2048ull * 1024 * 2);
  uint16_t* wT_q   = (uint16_t*)alloc(1024ull * 1024 * 2);
  uint16_t* wT_co  = (uint16_t*)alloc(1024ull * 1024 * 2);
  uint16_t* wT_fc1 = (uint16_t*)alloc(2048ull * 1024 * 2);
  uint16_t* wT_fc2 = (uint16_t*)alloc(1024ull * 2048 * 2);
  uint16_t* QKV    = (uint16_t*)alloc(3ull * 4194304 * 2);  // Q|K|Vt, reused as CQ|CK|CVt
  uint16_t* SA     = (uint16_t*)alloc(4194304ull * 2);      // attn out merged (both attns)
  float*    YATT   = (float*)alloc(4194304ull * 4);         // y_att f32; later F1 (bf16)
  float*    TMP    = (float*)alloc(4194304ull * 4);         // pre-LN f32, reused 3x
  uint16_t* YCB    = (uint16_t*)alloc(4194304ull * 2);      // y_cross bf16

  const dim3 blk(256);

  prep<<<dim3(20480), blk, 0, stream>>>(x, y, xb, yb,
                                        qkv_w, wT_qkv, ao_w, wT_ao, kv_w, wT_kv,
                                        q_w, wT_q, co_w, wT_co, fc1_w, wT_fc1, fc2_w, wT_fc2);

  // self-attention branch
  gemm_bt<EP_QKV><<<dim3(24, 32), blk, 0, stream>>>(yb, wT_qkv, qkv_b, QKV, nullptr, 4096, 3072, 1024);
  attn_fused<true><<<dim3(16, 64), blk, 0, stream>>>(QKV, QKV + 4194304, QKV + 2 * 4194304, SA);
  gemm_bt<EP_RES_F32RES><<<dim3(8, 32), blk, 0, stream>>>(SA, wT_ao, ao_b, TMP, y, 4096, 1024, 1024);
  ln_kernel<<<dim3(4096), blk, 0, stream>>>(TMP, ln1_g, ln1_b, nullptr, YATT, nullptr);
  // cross-attention branch (kv from x, q from original y)
  gemm_bt<EP_SCKV><<<dim3(16, 32), blk, 0, stream>>>(xb, wT_kv, kv_b, QKV + 4194304, nullptr, 4096, 2048, 1024);
  gemm_bt<EP_Q><<<dim3(8, 32), blk, 0, stream>>>(yb, wT_q, q_b, QKV, nullptr, 4096, 1024, 1024);
  attn_fused<false><<<dim3(16, 64), blk, 0, stream>>>(QKV, QKV + 4194304, QKV + 2 * 4194304, SA);
  gemm_bt<EP_F32><<<dim3(8, 32), blk, 0, stream>>>(SA, wT_co, co_b, TMP, nullptr, 4096, 1024, 1024);
  ln_kernel<<<dim3(4096), blk, 0, stream>>>(TMP, ln2_g, ln2_b, YATT, nullptr, YCB);
  // feedforward
  gemm_bt<EP_RELU><<<dim3(16, 32), blk, 0, stream>>>(YCB, wT_fc1, fc1_b, (uint16_t*)YATT, nullptr, 4096, 2048, 1024);
  gemm_bt<EP_RES_B16RES><<<dim3(8, 32), blk, 0, stream>>>((const uint16_t*)YATT, wT_fc2, fc2_b, TMP, YCB, 4096, 1024, 2048);
  ln_kernel<<<dim3(4096), blk, 0, stream>>>(TMP, ln3_g, ln3_b, nullptr, (float*)d_out, nullptr);
}

// Round 12
// 512.178 us; speedup vs baseline: 1.3056x; 1.0590x over previous
//
#include <hip/hip_runtime.h>
#include <cstdint>
#include <cstddef>

// DecoderLayer on MI355X (gfx950). Inputs f32, output f32, bf16 MFMA compute.
// B=4 S=1024 D=1024 H=16 DK=64 HID=2048

#define DEV __device__ __forceinline__

typedef __bf16 bf16x8 __attribute__((ext_vector_type(8)));
typedef float f32x4 __attribute__((ext_vector_type(4)));

DEV float bf2f(uint16_t h) { return __builtin_bit_cast(float, (uint32_t)h << 16); }
DEV uint16_t f2bf(float f) {
  uint32_t u = __builtin_bit_cast(uint32_t, f);
  return (uint16_t)((u + 0x7fffu + ((u >> 16) & 1u)) >> 16);
}

DEV void gload16(const void* g, void* l) {
  __builtin_amdgcn_global_load_lds((const __attribute__((address_space(1))) void*)g,
                                   (__attribute__((address_space(3))) void*)l, 16, 0, 0);
}

// ---------------------------------------------------------------- prep
// One kernel: cvt x,y (f32->bf16) + transpose all 7 weights (f32 KxN -> bf16 NxK).
// Blocks 0..8191: cvt (4096 for x, 4096 for y). Blocks 8192..20479: transposes.
__global__ __launch_bounds__(256) void prep(
    const float* __restrict__ x, const float* __restrict__ y,
    uint16_t* __restrict__ xb, uint16_t* __restrict__ yb,
    const float* __restrict__ w0, uint16_t* __restrict__ t0,   // qkv 1024x3072
    const float* __restrict__ w1, uint16_t* __restrict__ t1,   // ao  1024x1024
    const float* __restrict__ w2, uint16_t* __restrict__ t2,   // kv  1024x2048
    const float* __restrict__ w3, uint16_t* __restrict__ t3,   // q   1024x1024
    const float* __restrict__ w4, uint16_t* __restrict__ t4,   // co  1024x1024
    const float* __restrict__ w5, uint16_t* __restrict__ t5,   // fc1 1024x2048
    const float* __restrict__ w6, uint16_t* __restrict__ t6) { // fc2 2048x1024
  int bid = blockIdx.x;
  const int tid = threadIdx.x;
  if (bid < 8192) {
    const float* src = (bid < 4096) ? x : y;
    uint16_t* dst = (bid < 4096) ? xb : yb;
    const int i = (bid & 4095) * 256 + tid;
    const float4 v = ((const float4*)src)[i];
    const uint32_t lo = (uint32_t)f2bf(v.x) | ((uint32_t)f2bf(v.y) << 16);
    const uint32_t hi = (uint32_t)f2bf(v.z) | ((uint32_t)f2bf(v.w) << 16);
    ((uint2*)dst)[i] = make_uint2(lo, hi);
    return;
  }
  bid -= 8192;
  const float* W; uint16_t* T; int K, N, tile;
  if (bid < 3072)       { W = w0; T = t0; K = 1024; N = 3072; tile = bid; }
  else if (bid < 4096)  { W = w1; T = t1; K = 1024; N = 1024; tile = bid - 3072; }
  else if (bid < 6144)  { W = w2; T = t2; K = 1024; N = 2048; tile = bid - 4096; }
  else if (bid < 7168)  { W = w3; T = t3; K = 1024; N = 1024; tile = bid - 6144; }
  else if (bid < 8192)  { W = w4; T = t4; K = 1024; N = 1024; tile = bid - 7168; }
  else if (bid < 10240) { W = w5; T = t5; K = 1024; N = 2048; tile = bid - 8192; }
  else                  { W = w6; T = t6; K = 2048; N = 1024; tile = bid - 10240; }
  const int ntx = N >> 5;
  const int n0 = (tile % ntx) * 32, k0 = (tile / ntx) * 32;
  __shared__ float t[32][33];
  const int tx = tid & 31, ty = tid >> 5;
#pragma unroll
  for (int i = 0; i < 32; i += 8)
    t[ty + i][tx] = W[(size_t)(k0 + ty + i) * N + n0 + tx];
  __syncthreads();
#pragma unroll
  for (int i = 0; i < 32; i += 8)
    T[(size_t)(n0 + ty + i) * K + k0 + tx] = f2bf(t[tx][ty + i]);
}

// ---------------------------------------------------------------- GEMM
// C[M][N] = A[M][K] @ W[K][N] + bias(f32), W pre-transposed as Bt[N][K] bf16.
// 128x128 tile, BK=32, 4 waves (2x2 of 64x64), mfma_f32_16x16x32_bf16.
enum { EP_QKV = 0, EP_RES_F32RES, EP_SCKV, EP_Q, EP_F32, EP_RELU, EP_RES_B16RES };

template <int EPI>
__global__ __launch_bounds__(256) void gemm_bt(const uint16_t* __restrict__ A,
                                               const uint16_t* __restrict__ Bt,
                                               const float* __restrict__ bias,
                                               void* __restrict__ out0,
                                               const void* __restrict__ res,
                                               int M, int N, int K) {
  __shared__ __align__(16) uint16_t As[128 * 32];
  __shared__ __align__(16) uint16_t Bs[128 * 32];
  const int tid = threadIdx.x;
  const int wid = tid >> 6, lane = tid & 63;
  const int g = lane >> 4, lr = lane & 15;
  const int wr = wid >> 1, wc = wid & 1;
  const int m0 = blockIdx.y * 128, n0 = blockIdx.x * 128;

  const char* Ab = (const char*)A;
  const char* Bb = (const char*)Bt;
  const size_t rs = (size_t)K * 2;

  // staging: 8 chunks of 1KB per tile (16 rows x 64B); wave w does chunks 2w,2w+1
  const int rc = lane >> 2;                                  // row within chunk
  const int scb = ((lane & 3) << 4) ^ ((rc & 3) << 4);       // swizzled src col byte

  // fragment read offsets (swizzle: byte ^= (row&3)<<4), per-lane constants
  int aoff[4], boff[4];
#pragma unroll
  for (int m = 0; m < 4; ++m) {
    const int row = wr * 64 + m * 16 + lr;
    aoff[m] = row * 64 + ((g * 16) ^ ((row & 3) << 4));
  }
#pragma unroll
  for (int n = 0; n < 4; ++n) {
    const int row = wc * 64 + n * 16 + lr;
    boff[n] = row * 64 + ((g * 16) ^ ((row & 3) << 4));
  }

  f32x4 acc[4][4] = {};
  const int nk = K >> 5;
  for (int kt = 0; kt < nk; ++kt) {
    __syncthreads();
#pragma unroll
    for (int i = 0; i < 2; ++i) {
      const int c = wid * 2 + i;
      gload16(Ab + (size_t)(m0 + c * 16 + rc) * rs + (size_t)kt * 64 + scb,
              (void*)((char*)As + c * 1024));
      gload16(Bb + (size_t)(n0 + c * 16 + rc) * rs + (size_t)kt * 64 + scb,
              (void*)((char*)Bs + c * 1024));
    }
    asm volatile("s_waitcnt vmcnt(0)" ::: "memory");
    __syncthreads();

    bf16x8 av[4], bv[4];
#pragma unroll
    for (int m = 0; m < 4; ++m) av[m] = *(const bf16x8*)((const char*)As + aoff[m]);
#pragma unroll
    for (int n = 0; n < 4; ++n) bv[n] = *(const bf16x8*)((const char*)Bs + boff[n]);
#pragma unroll
    for (int m = 0; m < 4; ++m)
#pragma unroll
      for (int n = 0; n < 4; ++n)
        acc[m][n] = __builtin_amdgcn_mfma_f32_16x16x32_bf16(av[m], bv[n], acc[m][n], 0, 0, 0);
  }

  // epilogue: C/D layout row=(lane>>4)*4+r, col=lane&15
#pragma unroll
  for (int m = 0; m < 4; ++m) {
#pragma unroll
    for (int n = 0; n < 4; ++n) {
      const int gcol = n0 + wc * 64 + n * 16 + lr;
      const float bb = bias[gcol];
#pragma unroll
      for (int r = 0; r < 4; ++r) {
        const int grow = m0 + wr * 64 + m * 16 + g * 4 + r;
        float v = acc[m][n][r] + bb;
        if constexpr (EPI == EP_QKV) {
          // qkv: per-head split AFTER _heads: h=n/192, part=(n%192)/64
          const int b = grow >> 10, s = grow & 1023;
          const int h = gcol / 192;
          const int rr = gcol - h * 192;
          const int part = rr >> 6, d = rr & 63;
          const int bh = b * 16 + h;
          uint16_t* base = (uint16_t*)out0;
          if (part == 2)
            base[2u * 4194304u + ((size_t)bh * 64 + d) * 1024 + s] = f2bf(v);  // Vt[bh][d][s]
          else
            base[(size_t)part * 4194304u + ((size_t)bh * 1024 + s) * 64 + d] = f2bf(v);
        } else if constexpr (EPI == EP_SCKV) {
          // kv: h=n>>7, part=(n>>6)&1 (ck then cv)
          const int b = grow >> 10, s = grow & 1023;
          const int h = gcol >> 7, part = (gcol >> 6) & 1, d = gcol & 63;
          const int bh = b * 16 + h;
          uint16_t* base = (uint16_t*)out0;  // CK; CVt = base + 4194304
          if (part == 0)
            base[((size_t)bh * 1024 + s) * 64 + d] = f2bf(v);
          else
            base[4194304u + ((size_t)bh * 64 + d) * 1024 + s] = f2bf(v);
        } else if constexpr (EPI == EP_Q) {
          const int b = grow >> 10, s = grow & 1023;
          const int h = gcol >> 6, d = gcol & 63;
          ((uint16_t*)out0)[((size_t)(b * 16 + h) * 1024 + s) * 64 + d] = f2bf(v);
        } else if constexpr (EPI == EP_RES_F32RES) {
          v += ((const float*)res)[(size_t)grow * N + gcol];
          ((float*)out0)[(size_t)grow * N + gcol] = v;
        } else if constexpr (EPI == EP_F32) {
          ((float*)out0)[(size_t)grow * N + gcol] = v;
        } else if constexpr (EPI == EP_RELU) {
          ((uint16_t*)out0)[(size_t)grow * N + gcol] = f2bf(v > 0.f ? v : 0.f);
        } else if constexpr (EPI == EP_RES_B16RES) {
          v += bf2f(((const uint16_t*)res)[(size_t)grow * N + gcol]);
          ((float*)out0)[(size_t)grow * N + gcol] = v;
        }
      }
    }
  }
}

// ---------------------------------------------------------------- attention
// Fused flash attention, SWAPPED QK^T (mfma(K,Q)) so each lane's 16 score values
// all belong to ONE q-row (q=q0+lr, k=n*16+g*4+r): softmax = in-lane trees +
// 2 shfl_xor (16,32) + ONE m/l state. exp2-domain (SCALE=0.125*log2e).
// Double-buffered K/V LDS staging via global_load_lds; wave-private P LDS.
// Q,K: [BH][S][64] bf16; Vt: [BH][64][S] bf16. O merged: [B][S][H*64] bf16.
// grid(16, B*H) with causal qb pairing remap; 4 waves x 16 q-rows. LDS 40KB.
template <bool CAUSAL>
__global__ __launch_bounds__(256) void attn_fused(const uint16_t* __restrict__ Qp,
                                                  const uint16_t* __restrict__ Kp,
                                                  const uint16_t* __restrict__ Vtp,
                                                  uint16_t* __restrict__ O) {
  __shared__ __align__(16) uint16_t Kl[2][64 * 64];
  __shared__ __align__(16) uint16_t Vl[2][64 * 64];
  __shared__ __align__(16) uint16_t Pl[4][16 * 64];
  const int tid = threadIdx.x, wid = tid >> 6, lane = tid & 63;
  const int g = lane >> 4, lr = lane & 15;
  const int qbx = blockIdx.x, bh = blockIdx.y;
  // causal load-balance: pair long and short q-blocks ((0,15),(1,14),...)
  const int qb = CAUSAL ? ((qbx & 1) ? (15 - (qbx >> 1)) : (qbx >> 1)) : qbx;
  const char* Qb = (const char*)(Qp + (size_t)bh * 65536);
  const char* Kb = (const char*)(Kp + (size_t)bh * 65536);
  const char* Vb = (const char*)(Vtp + (size_t)bh * 65536);
  const int q0 = qb * 64 + wid * 16;
  const float SCALE = 0.18033688011112042f;  // 0.125 * log2(e)

  bf16x8 aq[2];
#pragma unroll
  for (int ks = 0; ks < 2; ++ks)
    aq[ks] = *(const bf16x8*)(Qb + ((size_t)(q0 + lr) * 64 + ks * 32 + g * 8) * 2);

  float m_run = -1e30f, l_run = 0.f;
  f32x4 oacc[4] = {};

  const int rc = lane >> 3;                             // row within 8-row chunk
  const int scb = ((lane & 7) << 4) ^ (rc << 4);        // swizzled src col byte
  const int nkt = CAUSAL ? (qb + 1) : 16;
  char* Pb = (char*)Pl[wid];

  // stage tile kt into buffer bufi: 8 chunks of 1KB each for K and V (2/wave)
  auto stage = [&](int kt, int bufi) {
#pragma unroll
    for (int i = 0; i < 2; ++i) {
      const int c = wid * 2 + i;
      gload16(Kb + (size_t)(kt * 64 + c * 8 + rc) * 128 + scb,
              (void*)((char*)Kl[bufi] + c * 1024));
      gload16(Vb + (size_t)(c * 8 + rc) * 2048 + kt * 128 + scb,
              (void*)((char*)Vl[bufi] + c * 1024));
    }
  };

  stage(0, 0);
  asm volatile("s_waitcnt vmcnt(0)" ::: "memory");
  __syncthreads();

  for (int kt = 0; kt < nkt; ++kt) {
    const int cur = kt & 1;
    if (kt + 1 < nkt) stage(kt + 1, cur ^ 1);   // prefetch overlaps this tile's compute
    const char* Kc = (const char*)Kl[cur];
    const char* Vc = (const char*)Vl[cur];
    // diagonal tile: n-subtiles entirely above the diagonal carry no data
    const int nlim = (CAUSAL && kt == qb) ? wid : 3;

    // S^T = (K Q^T): lane holds p[n][r] = S[q=q0+lr][k=kt*64+n*16+g*4+r] (log2 dom)
    float p[4][4];
#pragma unroll
    for (int n = 0; n < 4; ++n) {
      if (n <= nlim) {
        f32x4 t = {};
#pragma unroll
        for (int ks = 0; ks < 2; ++ks) {
          const int row = n * 16 + lr;
          bf16x8 bk = *(const bf16x8*)(Kc + row * 128 + ((ks * 64 + g * 16) ^ ((row & 7) << 4)));
          t = __builtin_amdgcn_mfma_f32_16x16x32_bf16(bk, aq[ks], t, 0, 0, 0);  // SWAPPED
        }
#pragma unroll
        for (int r = 0; r < 4; ++r) p[n][r] = t[r] * SCALE;
      } else {
#pragma unroll
        for (int r = 0; r < 4; ++r) p[n][r] = -1e9f;
      }
    }
    if (CAUSAL && kt == qb) {
      const int q_abs = q0 + lr;
#pragma unroll
      for (int n = 0; n < 4; ++n)
#pragma unroll
        for (int r = 0; r < 4; ++r)
          if (kt * 64 + n * 16 + g * 4 + r > q_abs) p[n][r] = -1e9f;
    }

    // online softmax, all values lane-local for one q-row
    float mx = -1e30f;
#pragma unroll
    for (int n = 0; n < 4; ++n)
#pragma unroll
      for (int r = 0; r < 4; ++r) mx = fmaxf(mx, p[n][r]);
    mx = fmaxf(mx, __shfl_xor(mx, 16));
    mx = fmaxf(mx, __shfl_xor(mx, 32));
    const float mnew = fmaxf(m_run, mx);
    const float f = exp2f(m_run - mnew);
    m_run = mnew;
    float ls = 0.f;
#pragma unroll
    for (int n = 0; n < 4; ++n)
#pragma unroll
      for (int r = 0; r < 4; ++r) {
        const float e = exp2f(p[n][r] - mnew);
        p[n][r] = e;
        ls += e;
      }
    ls += __shfl_xor(ls, 16);
    ls += __shfl_xor(ls, 32);
    l_run = l_run * f + ls;
    // broadcast rescale factors for oacc rows (q_local = g*4+r lives in lane g*4+r)
    float fb[4];
#pragma unroll
    for (int r = 0; r < 4; ++r) fb[r] = __shfl(f, g * 4 + r);
#pragma unroll
    for (int n2 = 0; n2 < 4; ++n2)
#pragma unroll
      for (int r = 0; r < 4; ++r) oacc[n2][r] *= fb[r];

    // P -> wave-private LDS: logical row=q=lr, col-byte=2*k, packed b64 writes
#pragma unroll
    for (int n = 0; n < 4; ++n) {
      const uint32_t w0 = (uint32_t)f2bf(p[n][0]) | ((uint32_t)f2bf(p[n][1]) << 16);
      const uint32_t w1 = (uint32_t)f2bf(p[n][2]) | ((uint32_t)f2bf(p[n][3]) << 16);
      *(uint2*)(Pb + lr * 128 + ((n * 32 + g * 8) ^ ((lr & 7) << 4))) = make_uint2(w0, w1);
    }
    asm volatile("s_waitcnt lgkmcnt(0)" ::: "memory");
#pragma unroll
    for (int ks = 0; ks < 2; ++ks) {
      bf16x8 pa = *(const bf16x8*)(Pb + lr * 128 + ((ks * 64 + g * 16) ^ ((lr & 7) << 4)));
#pragma unroll
      for (int n2 = 0; n2 < 4; ++n2) {
        const int row = n2 * 16 + lr;
        bf16x8 bv = *(const bf16x8*)(Vc + row * 128 + ((ks * 64 + g * 16) ^ ((row & 7) << 4)));
        oacc[n2] = __builtin_amdgcn_mfma_f32_16x16x32_bf16(pa, bv, oacc[n2], 0, 0, 0);
      }
    }
    asm volatile("s_waitcnt vmcnt(0)" ::: "memory");  // next tile's stage has landed
    __syncthreads();
  }

  // epilogue: oacc[n2][r] = O[q=q0+g*4+r][d=n2*16+lr]; l for that q via shfl
  float lb[4];
#pragma unroll
  for (int r = 0; r < 4; ++r) lb[r] = __shfl(l_run, g * 4 + r);
  const int b = bh >> 4, h = bh & 15;
#pragma unroll
  for (int n2 = 0; n2 < 4; ++n2)
#pragma unroll
    for (int r = 0; r < 4; ++r) {
      const int q = q0 + g * 4 + r, d = n2 * 16 + lr;
      const float v = oacc[n2][r] / lb[r];
      O[(size_t)(b * 1024 + q) * 1024 + h * 64 + d] = f2bf(v);
    }
}

// ---------------------------------------------------------------- layernorm
// One 256-thread block per row (D=1024). fp32 in; optional post-add; f32/bf16 out.
__global__ __launch_bounds__(256) void ln_kernel(const float* __restrict__ in,
                                                 const float* __restrict__ gam,
                                                 const float* __restrict__ bet,
                                                 const float* __restrict__ addend,
                                                 float* __restrict__ outf,
                                                 uint16_t* __restrict__ outb) {
  __shared__ float red[4];
  const int tid = threadIdx.x;
  const size_t row = blockIdx.x;
  const float4 v = ((const float4*)(in + row * 1024))[tid];
  float s = v.x + v.y + v.z + v.w;
#pragma unroll
  for (int o = 1; o < 64; o <<= 1) s += __shfl_xor(s, o);
  const int wid = tid >> 6, lane = tid & 63;
  if (lane == 0) red[wid] = s;
  __syncthreads();
  s = red[0] + red[1] + red[2] + red[3];
  const float mu = s * (1.f / 1024.f);
  const float d0 = v.x - mu, d1 = v.y - mu, d2 = v.z - mu, d3 = v.w - mu;
  float sq = d0 * d0 + d1 * d1 + d2 * d2 + d3 * d3;
  __syncthreads();
#pragma unroll
  for (int o = 1; o < 64; o <<= 1) sq += __shfl_xor(sq, o);
  if (lane == 0) red[wid] = sq;
  __syncthreads();
  sq = red[0] + red[1] + red[2] + red[3];
  const float inv = rsqrtf(sq * (1.f / 1024.f) + 1e-5f);
  const float4 gv = ((const float4*)(gam))[tid];
  const float4 bv = ((const float4*)(bet))[tid];
  float o0 = d0 * inv * gv.x + bv.x;
  float o1 = d1 * inv * gv.y + bv.y;
  float o2 = d2 * inv * gv.z + bv.z;
  float o3 = d3 * inv * gv.w + bv.w;
  if (addend) {
    const float4 a = ((const float4*)(addend + row * 1024))[tid];
    o0 += a.x; o1 += a.y; o2 += a.z; o3 += a.w;
  }
  if (outf)
    ((float4*)(outf + row * 1024))[tid] = make_float4(o0, o1, o2, o3);
  if (outb) {
    const uint32_t w0 = (uint32_t)f2bf(o0) | ((uint32_t)f2bf(o1) << 16);
    const uint32_t w1 = (uint32_t)f2bf(o2) | ((uint32_t)f2bf(o3) << 16);
    ((uint2*)(outb + row * 1024))[tid] = make_uint2(w0, w1);
  }
}

// ---------------------------------------------------------------- launch
extern "C" void kernel_launch(void* const* d_in, const int* in_sizes, int n_in,
                              void* d_out, int out_size, void* d_ws, size_t ws_size,
                              hipStream_t stream) {
  (void)in_sizes; (void)n_in; (void)out_size; (void)ws_size;
  const float* x     = (const float*)d_in[0];
  const float* y     = (const float*)d_in[1];
  const float* qkv_w = (const float*)d_in[3];
  const float* qkv_b = (const float*)d_in[4];
  const float* ao_w  = (const float*)d_in[5];
  const float* ao_b  = (const float*)d_in[6];
  const float* kv_w  = (const float*)d_in[7];
  const float* kv_b  = (const float*)d_in[8];
  const float* q_w   = (const float*)d_in[9];
  const float* q_b   = (const float*)d_in[10];
  const float* co_w  = (const float*)d_in[11];
  const float* co_b  = (const float*)d_in[12];
  const float* fc1_w = (const float*)d_in[13];
  const float* fc1_b = (const float*)d_in[14];
  const float* fc2_w = (const float*)d_in[15];
  const float* fc2_b = (const float*)d_in[16];
  const float* ln1_g = (const float*)d_in[17];
  const float* ln1_b = (const float*)d_in[18];
  const float* ln2_g = (const float*)d_in[19];
  const float* ln2_b = (const float*)d_in[20];
  const float* ln3_g = (const float*)d_in[21];
  const float* ln3_b = (const float*)d_in[22];

  char* ws = (char*)d_ws;
  size_t off = 0;
  auto alloc = [&](size_t bytes) {
    char* p = ws + off;
    off += (bytes + 255) & ~(size_t)255;
    return p;
  };
  uint16_t* xb     = (uint16_t*)alloc(4194304ull * 2);      // x bf16
  uint16_t* yb     = (uint16_t*)alloc(4194304ull * 2);      // y bf16
  uint16_t* wT_qkv = (uint16_t*)alloc(3072ull * 1024 * 2);
  uint16_t* wT_ao  = (uint16_t*)alloc(1024ull * 1024 * 2);
  uint16_t* wT_kv  = (uint16_t*)alloc(2048ull * 1024 * 2);
  uint16_t* wT_q   = (uint16_t*)alloc(1024ull * 1024 * 2);
  uint16_t* wT_co  = (uint16_t*)alloc(1024ull * 1024 * 2);
  uint16_t* wT_fc1 = (uint16_t*)alloc(2048ull * 1024 * 2);
  uint16_t* wT_fc2 = (uint16_t*)alloc(1024ull * 2048 * 2);
  uint16_t* QKV    = (uint16_t*)alloc(3ull * 4194304 * 2);  // Q|K|Vt, reused as CQ|CK|CVt
  uint16_t* SA     = (uint16_t*)alloc(4194304ull * 2);      // attn out merged (both attns)
  float*    YATT   = (float*)alloc(4194304ull * 4);         // y_att f32; later F1 (bf16)
  float*    TMP    = (float*)alloc(4194304ull * 4);         // pre-LN f32, reused 3x
  uint16_t* YCB    = (uint16_t*)alloc(4194304ull * 2);      // y_cross bf16

  const dim3 blk(256);

  prep<<<dim3(20480), blk, 0, stream>>>(x, y, xb, yb,
                                        qkv_w, wT_qkv, ao_w, wT_ao, kv_w, wT_kv,
                                        q_w, wT_q, co_w, wT_co, fc1_w, wT_fc1, fc2_w, wT_fc2);

  // self-attention branch
  gemm_bt<EP_QKV><<<dim3(24, 32), blk, 0, stream>>>(yb, wT_qkv, qkv_b, QKV, nullptr, 4096, 3072, 1024);
  attn_fused<true><<<dim3(16, 64), blk, 0, stream>>>(QKV, QKV + 4194304, QKV + 2 * 4194304, SA);
  gemm_bt<EP_RES_F32RES><<<dim3(8, 32), blk, 0, stream>>>(SA, wT_ao, ao_b, TMP, y, 4096, 1024, 1024);
  ln_kernel<<<dim3(4096), blk, 0, stream>>>(TMP, ln1_g, ln1_b, nullptr, YATT, nullptr);
  // cross-attention branch (kv from x, q from original y)
  gemm_bt<EP_SCKV><<<dim3(16, 32), blk, 0, stream>>>(xb, wT_kv, kv_b, QKV + 4194304, nullptr, 4096, 2048, 1024);
  gemm_bt<EP_Q><<<dim3(8, 32), blk, 0, stream>>>(yb, wT_q, q_b, QKV, nullptr, 4096, 1024, 1024);
  attn_fused<false><<<dim3(16, 64), blk, 0, stream>>>(QKV, QKV + 4194304, QKV + 2 * 4194304, SA);
  gemm_bt<EP_F32><<<dim3(8, 32), blk, 0, stream>>>(SA, wT_co, co_b, TMP, nullptr, 4096, 1024, 1024);
  ln_kernel<<<dim3(4096), blk, 0, stream>>>(TMP, ln2_g, ln2_b, YATT, nullptr, YCB);
  // feedforward
  gemm_bt<EP_RELU><<<dim3(16, 32), blk, 0, stream>>>(YCB, wT_fc1, fc1_b, (uint16_t*)YATT, nullptr, 4096, 2048, 1024);
  gemm_bt<EP_RES_B16RES><<<dim3(8, 32), blk, 0, stream>>>((const uint16_t*)YATT, wT_fc2, fc2_b, TMP, YCB, 4096, 1024, 2048);
  ln_kernel<<<dim3(4096), blk, 0, stream>>>(TMP, ln3_g, ln3_b, nullptr, (float*)d_out, nullptr);
}

// Round 13
// 493.101 us; speedup vs baseline: 1.3561x; 1.0387x over previous
//
#include <hip/hip_runtime.h>
#include <cstdint>
#include <cstddef>

// DecoderLayer on MI355X (gfx950). Inputs f32, output f32, bf16 MFMA compute.
// B=4 S=1024 D=1024 H=16 DK=64 HID=2048

#define DEV __device__ __forceinline__

typedef __bf16 bf16x8 __attribute__((ext_vector_type(8)));
typedef float f32x4 __attribute__((ext_vector_type(4)));

DEV float bf2f(uint16_t h) { return __builtin_bit_cast(float, (uint32_t)h << 16); }
DEV uint16_t f2bf(float f) {
  uint32_t u = __builtin_bit_cast(uint32_t, f);
  return (uint16_t)((u + 0x7fffu + ((u >> 16) & 1u)) >> 16);
}

DEV void gload16(const void* g, void* l) {
  __builtin_amdgcn_global_load_lds((const __attribute__((address_space(1))) void*)g,
                                   (__attribute__((address_space(3))) void*)l, 16, 0, 0);
}

// ---------------------------------------------------------------- prep
// One kernel: cvt x,y (f32->bf16) + transpose all 7 weights (f32 KxN -> bf16 NxK).
// Blocks 0..8191: cvt (4096 for x, 4096 for y). Blocks 8192..20479: transposes.
__global__ __launch_bounds__(256) void prep(
    const float* __restrict__ x, const float* __restrict__ y,
    uint16_t* __restrict__ xb, uint16_t* __restrict__ yb,
    const float* __restrict__ w0, uint16_t* __restrict__ t0,   // qkv 1024x3072
    const float* __restrict__ w1, uint16_t* __restrict__ t1,   // ao  1024x1024
    const float* __restrict__ w2, uint16_t* __restrict__ t2,   // kv  1024x2048
    const float* __restrict__ w3, uint16_t* __restrict__ t3,   // q   1024x1024
    const float* __restrict__ w4, uint16_t* __restrict__ t4,   // co  1024x1024
    const float* __restrict__ w5, uint16_t* __restrict__ t5,   // fc1 1024x2048
    const float* __restrict__ w6, uint16_t* __restrict__ t6) { // fc2 2048x1024
  int bid = blockIdx.x;
  const int tid = threadIdx.x;
  if (bid < 8192) {
    const float* src = (bid < 4096) ? x : y;
    uint16_t* dst = (bid < 4096) ? xb : yb;
    const int i = (bid & 4095) * 256 + tid;
    const float4 v = ((const float4*)src)[i];
    const uint32_t lo = (uint32_t)f2bf(v.x) | ((uint32_t)f2bf(v.y) << 16);
    const uint32_t hi = (uint32_t)f2bf(v.z) | ((uint32_t)f2bf(v.w) << 16);
    ((uint2*)dst)[i] = make_uint2(lo, hi);
    return;
  }
  bid -= 8192;
  const float* W; uint16_t* T; int K, N, tile;
  if (bid < 3072)       { W = w0; T = t0; K = 1024; N = 3072; tile = bid; }
  else if (bid < 4096)  { W = w1; T = t1; K = 1024; N = 1024; tile = bid - 3072; }
  else if (bid < 6144)  { W = w2; T = t2; K = 1024; N = 2048; tile = bid - 4096; }
  else if (bid < 7168)  { W = w3; T = t3; K = 1024; N = 1024; tile = bid - 6144; }
  else if (bid < 8192)  { W = w4; T = t4; K = 1024; N = 1024; tile = bid - 7168; }
  else if (bid < 10240) { W = w5; T = t5; K = 1024; N = 2048; tile = bid - 8192; }
  else                  { W = w6; T = t6; K = 2048; N = 1024; tile = bid - 10240; }
  const int ntx = N >> 5;
  const int n0 = (tile % ntx) * 32, k0 = (tile / ntx) * 32;
  __shared__ float t[32][33];
  const int tx = tid & 31, ty = tid >> 5;
#pragma unroll
  for (int i = 0; i < 32; i += 8)
    t[ty + i][tx] = W[(size_t)(k0 + ty + i) * N + n0 + tx];
  __syncthreads();
#pragma unroll
  for (int i = 0; i < 32; i += 8)
    T[(size_t)(n0 + ty + i) * K + k0 + tx] = f2bf(t[tx][ty + i]);
}

// ---------------------------------------------------------------- GEMM
// C[M][N] = A[M][K] @ W[K][N] + bias(f32), W pre-transposed as Bt[N][K] bf16.
// 128x128 tile, BK=32, 4 waves (2x2 of 64x64), mfma_f32_16x16x32_bf16.
// 2-phase pipeline (T3-minimum): double-buffered LDS; stage(kt+1) issued BEFORE
// compute(kt); single vmcnt(0)+barrier per K-tile so loads land under compute.
enum { EP_QKV = 0, EP_RES_F32RES, EP_SCKV, EP_Q, EP_F32, EP_RELU, EP_RES_B16RES };

template <int EPI>
__global__ __launch_bounds__(256) void gemm_bt(const uint16_t* __restrict__ A,
                                               const uint16_t* __restrict__ Bt,
                                               const float* __restrict__ bias,
                                               void* __restrict__ out0,
                                               const void* __restrict__ res,
                                               int M, int N, int K) {
  __shared__ __align__(16) uint16_t As[2][128 * 32];
  __shared__ __align__(16) uint16_t Bs[2][128 * 32];
  const int tid = threadIdx.x;
  const int wid = tid >> 6, lane = tid & 63;
  const int g = lane >> 4, lr = lane & 15;
  const int wr = wid >> 1, wc = wid & 1;
  const int m0 = blockIdx.y * 128, n0 = blockIdx.x * 128;

  const char* Ab = (const char*)A;
  const char* Bb = (const char*)Bt;
  const size_t rs = (size_t)K * 2;

  // staging: 8 chunks of 1KB per tile (16 rows x 64B); wave w does chunks 2w,2w+1
  const int rc = lane >> 2;                                  // row within chunk
  const int scb = ((lane & 3) << 4) ^ ((rc & 3) << 4);       // swizzled src col byte

  // fragment read offsets (swizzle: byte ^= (row&3)<<4), per-lane constants
  int aoff[4], boff[4];
#pragma unroll
  for (int m = 0; m < 4; ++m) {
    const int row = wr * 64 + m * 16 + lr;
    aoff[m] = row * 64 + ((g * 16) ^ ((row & 3) << 4));
  }
#pragma unroll
  for (int n = 0; n < 4; ++n) {
    const int row = wc * 64 + n * 16 + lr;
    boff[n] = row * 64 + ((g * 16) ^ ((row & 3) << 4));
  }

  // stage K-tile kt into buffer bufi (4 gload16 per wave)
  auto stage = [&](int kt, int bufi) {
#pragma unroll
    for (int i = 0; i < 2; ++i) {
      const int c = wid * 2 + i;
      gload16(Ab + (size_t)(m0 + c * 16 + rc) * rs + (size_t)kt * 64 + scb,
              (void*)((char*)As[bufi] + c * 1024));
      gload16(Bb + (size_t)(n0 + c * 16 + rc) * rs + (size_t)kt * 64 + scb,
              (void*)((char*)Bs[bufi] + c * 1024));
    }
  };

  f32x4 acc[4][4] = {};
  const int nk = K >> 5;

  stage(0, 0);
  asm volatile("s_waitcnt vmcnt(0)" ::: "memory");
  __syncthreads();

  for (int kt = 0; kt < nk; ++kt) {
    const int cur = kt & 1;
    if (kt + 1 < nk) stage(kt + 1, cur ^ 1);  // prefetch overlaps this tile's MFMAs

    bf16x8 av[4], bv[4];
#pragma unroll
    for (int m = 0; m < 4; ++m) av[m] = *(const bf16x8*)((const char*)As[cur] + aoff[m]);
#pragma unroll
    for (int n = 0; n < 4; ++n) bv[n] = *(const bf16x8*)((const char*)Bs[cur] + boff[n]);
#pragma unroll
    for (int m = 0; m < 4; ++m)
#pragma unroll
      for (int n = 0; n < 4; ++n)
        acc[m][n] = __builtin_amdgcn_mfma_f32_16x16x32_bf16(av[m], bv[n], acc[m][n], 0, 0, 0);

    asm volatile("s_waitcnt vmcnt(0)" ::: "memory");  // next tile's stage has landed
    __syncthreads();
  }

  // epilogue: C/D layout row=(lane>>4)*4+r, col=lane&15
#pragma unroll
  for (int m = 0; m < 4; ++m) {
#pragma unroll
    for (int n = 0; n < 4; ++n) {
      const int gcol = n0 + wc * 64 + n * 16 + lr;
      const float bb = bias[gcol];
#pragma unroll
      for (int r = 0; r < 4; ++r) {
        const int grow = m0 + wr * 64 + m * 16 + g * 4 + r;
        float v = acc[m][n][r] + bb;
        if constexpr (EPI == EP_QKV) {
          // qkv: per-head split AFTER _heads: h=n/192, part=(n%192)/64
          const int b = grow >> 10, s = grow & 1023;
          const int h = gcol / 192;
          const int rr = gcol - h * 192;
          const int part = rr >> 6, d = rr & 63;
          const int bh = b * 16 + h;
          uint16_t* base = (uint16_t*)out0;
          if (part == 2)
            base[2u * 4194304u + ((size_t)bh * 64 + d) * 1024 + s] = f2bf(v);  // Vt[bh][d][s]
          else
            base[(size_t)part * 4194304u + ((size_t)bh * 1024 + s) * 64 + d] = f2bf(v);
        } else if constexpr (EPI == EP_SCKV) {
          // kv: h=n>>7, part=(n>>6)&1 (ck then cv)
          const int b = grow >> 10, s = grow & 1023;
          const int h = gcol >> 7, part = (gcol >> 6) & 1, d = gcol & 63;
          const int bh = b * 16 + h;
          uint16_t* base = (uint16_t*)out0;  // CK; CVt = base + 4194304
          if (part == 0)
            base[((size_t)bh * 1024 + s) * 64 + d] = f2bf(v);
          else
            base[4194304u + ((size_t)bh * 64 + d) * 1024 + s] = f2bf(v);
        } else if constexpr (EPI == EP_Q) {
          const int b = grow >> 10, s = grow & 1023;
          const int h = gcol >> 6, d = gcol & 63;
          ((uint16_t*)out0)[((size_t)(b * 16 + h) * 1024 + s) * 64 + d] = f2bf(v);
        } else if constexpr (EPI == EP_RES_F32RES) {
          v += ((const float*)res)[(size_t)grow * N + gcol];
          ((float*)out0)[(size_t)grow * N + gcol] = v;
        } else if constexpr (EPI == EP_F32) {
          ((float*)out0)[(size_t)grow * N + gcol] = v;
        } else if constexpr (EPI == EP_RELU) {
          ((uint16_t*)out0)[(size_t)grow * N + gcol] = f2bf(v > 0.f ? v : 0.f);
        } else if constexpr (EPI == EP_RES_B16RES) {
          v += bf2f(((const uint16_t*)res)[(size_t)grow * N + gcol]);
          ((float*)out0)[(size_t)grow * N + gcol] = v;
        }
      }
    }
  }
}

// ---------------------------------------------------------------- attention
// Fused flash attention, SWAPPED QK^T (mfma(K,Q)) so each lane's 16 score values
// all belong to ONE q-row (q=q0+lr, k=n*16+g*4+r): softmax = in-lane trees +
// 2 shfl_xor (16,32) + ONE m/l state. exp2-domain (SCALE=0.125*log2e).
// Double-buffered K/V LDS staging via global_load_lds; wave-private P LDS.
// Q,K: [BH][S][64] bf16; Vt: [BH][64][S] bf16. O merged: [B][S][H*64] bf16.
// grid(16, B*H) with causal qb pairing remap; 4 waves x 16 q-rows. LDS 40KB.
template <bool CAUSAL>
__global__ __launch_bounds__(256) void attn_fused(const uint16_t* __restrict__ Qp,
                                                  const uint16_t* __restrict__ Kp,
                                                  const uint16_t* __restrict__ Vtp,
                                                  uint16_t* __restrict__ O) {
  __shared__ __align__(16) uint16_t Kl[2][64 * 64];
  __shared__ __align__(16) uint16_t Vl[2][64 * 64];
  __shared__ __align__(16) uint16_t Pl[4][16 * 64];
  const int tid = threadIdx.x, wid = tid >> 6, lane = tid & 63;
  const int g = lane >> 4, lr = lane & 15;
  const int qbx = blockIdx.x, bh = blockIdx.y;
  // causal load-balance: pair long and short q-blocks ((0,15),(1,14),...)
  const int qb = CAUSAL ? ((qbx & 1) ? (15 - (qbx >> 1)) : (qbx >> 1)) : qbx;
  const char* Qb = (const char*)(Qp + (size_t)bh * 65536);
  const char* Kb = (const char*)(Kp + (size_t)bh * 65536);
  const char* Vb = (const char*)(Vtp + (size_t)bh * 65536);
  const int q0 = qb * 64 + wid * 16;
  const float SCALE = 0.18033688011112042f;  // 0.125 * log2(e)

  bf16x8 aq[2];
#pragma unroll
  for (int ks = 0; ks < 2; ++ks)
    aq[ks] = *(const bf16x8*)(Qb + ((size_t)(q0 + lr) * 64 + ks * 32 + g * 8) * 2);

  float m_run = -1e30f, l_run = 0.f;
  f32x4 oacc[4] = {};

  const int rc = lane >> 3;                             // row within 8-row chunk
  const int scb = ((lane & 7) << 4) ^ (rc << 4);        // swizzled src col byte
  const int nkt = CAUSAL ? (qb + 1) : 16;
  char* Pb = (char*)Pl[wid];

  // stage tile kt into buffer bufi: 8 chunks of 1KB each for K and V (2/wave)
  auto stage = [&](int kt, int bufi) {
#pragma unroll
    for (int i = 0; i < 2; ++i) {
      const int c = wid * 2 + i;
      gload16(Kb + (size_t)(kt * 64 + c * 8 + rc) * 128 + scb,
              (void*)((char*)Kl[bufi] + c * 1024));
      gload16(Vb + (size_t)(c * 8 + rc) * 2048 + kt * 128 + scb,
              (void*)((char*)Vl[bufi] + c * 1024));
    }
  };

  stage(0, 0);
  asm volatile("s_waitcnt vmcnt(0)" ::: "memory");
  __syncthreads();

  for (int kt = 0; kt < nkt; ++kt) {
    const int cur = kt & 1;
    if (kt + 1 < nkt) stage(kt + 1, cur ^ 1);   // prefetch overlaps this tile's compute
    const char* Kc = (const char*)Kl[cur];
    const char* Vc = (const char*)Vl[cur];
    // diagonal tile: n-subtiles entirely above the diagonal carry no data
    const int nlim = (CAUSAL && kt == qb) ? wid : 3;

    // S^T = (K Q^T): lane holds p[n][r] = S[q=q0+lr][k=kt*64+n*16+g*4+r] (log2 dom)
    float p[4][4];
#pragma unroll
    for (int n = 0; n < 4; ++n) {
      if (n <= nlim) {
        f32x4 t = {};
#pragma unroll
        for (int ks = 0; ks < 2; ++ks) {
          const int row = n * 16 + lr;
          bf16x8 bk = *(const bf16x8*)(Kc + row * 128 + ((ks * 64 + g * 16) ^ ((row & 7) << 4)));
          t = __builtin_amdgcn_mfma_f32_16x16x32_bf16(bk, aq[ks], t, 0, 0, 0);  // SWAPPED
        }
#pragma unroll
        for (int r = 0; r < 4; ++r) p[n][r] = t[r] * SCALE;
      } else {
#pragma unroll
        for (int r = 0; r < 4; ++r) p[n][r] = -1e9f;
      }
    }
    if (CAUSAL && kt == qb) {
      const int q_abs = q0 + lr;
#pragma unroll
      for (int n = 0; n < 4; ++n)
#pragma unroll
        for (int r = 0; r < 4; ++r)
          if (kt * 64 + n * 16 + g * 4 + r > q_abs) p[n][r] = -1e9f;
    }

    // online softmax, all values lane-local for one q-row
    float mx = -1e30f;
#pragma unroll
    for (int n = 0; n < 4; ++n)
#pragma unroll
      for (int r = 0; r < 4; ++r) mx = fmaxf(mx, p[n][r]);
    mx = fmaxf(mx, __shfl_xor(mx, 16));
    mx = fmaxf(mx, __shfl_xor(mx, 32));
    const float mnew = fmaxf(m_run, mx);
    const float f = exp2f(m_run - mnew);
    m_run = mnew;
    float ls = 0.f;
#pragma unroll
    for (int n = 0; n < 4; ++n)
#pragma unroll
      for (int r = 0; r < 4; ++r) {
        const float e = exp2f(p[n][r] - mnew);
        p[n][r] = e;
        ls += e;
      }
    ls += __shfl_xor(ls, 16);
    ls += __shfl_xor(ls, 32);
    l_run = l_run * f + ls;
    // broadcast rescale factors for oacc rows (q_local = g*4+r lives in lane g*4+r)
    float fb[4];
#pragma unroll
    for (int r = 0; r < 4; ++r) fb[r] = __shfl(f, g * 4 + r);
#pragma unroll
    for (int n2 = 0; n2 < 4; ++n2)
#pragma unroll
      for (int r = 0; r < 4; ++r) oacc[n2][r] *= fb[r];

    // P -> wave-private LDS: logical row=q=lr, col-byte=2*k, packed b64 writes
#pragma unroll
    for (int n = 0; n < 4; ++n) {
      const uint32_t w0 = (uint32_t)f2bf(p[n][0]) | ((uint32_t)f2bf(p[n][1]) << 16);
      const uint32_t w1 = (uint32_t)f2bf(p[n][2]) | ((uint32_t)f2bf(p[n][3]) << 16);
      *(uint2*)(Pb + lr * 128 + ((n * 32 + g * 8) ^ ((lr & 7) << 4))) = make_uint2(w0, w1);
    }
    asm volatile("s_waitcnt lgkmcnt(0)" ::: "memory");
#pragma unroll
    for (int ks = 0; ks < 2; ++ks) {
      bf16x8 pa = *(const bf16x8*)(Pb + lr * 128 + ((ks * 64 + g * 16) ^ ((lr & 7) << 4)));
#pragma unroll
      for (int n2 = 0; n2 < 4; ++n2) {
        const int row = n2 * 16 + lr;
        bf16x8 bv = *(const bf16x8*)(Vc + row * 128 + ((ks * 64 + g * 16) ^ ((row & 7) << 4)));
        oacc[n2] = __builtin_amdgcn_mfma_f32_16x16x32_bf16(pa, bv, oacc[n2], 0, 0, 0);
      }
    }
    asm volatile("s_waitcnt vmcnt(0)" ::: "memory");  // next tile's stage has landed
    __syncthreads();
  }

  // epilogue: oacc[n2][r] = O[q=q0+g*4+r][d=n2*16+lr]; l for that q via shfl
  float lb[4];
#pragma unroll
  for (int r = 0; r < 4; ++r) lb[r] = __shfl(l_run, g * 4 + r);
  const int b = bh >> 4, h = bh & 15;
#pragma unroll
  for (int n2 = 0; n2 < 4; ++n2)
#pragma unroll
    for (int r = 0; r < 4; ++r) {
      const int q = q0 + g * 4 + r, d = n2 * 16 + lr;
      const float v = oacc[n2][r] / lb[r];
      O[(size_t)(b * 1024 + q) * 1024 + h * 64 + d] = f2bf(v);
    }
}

// ---------------------------------------------------------------- layernorm
// One 256-thread block per row (D=1024). fp32 in; optional post-add; f32/bf16 out.
__global__ __launch_bounds__(256) void ln_kernel(const float* __restrict__ in,
                                                 const float* __restrict__ gam,
                                                 const float* __restrict__ bet,
                                                 const float* __restrict__ addend,
                                                 float* __restrict__ outf,
                                                 uint16_t* __restrict__ outb) {
  __shared__ float red[4];
  const int tid = threadIdx.x;
  const size_t row = blockIdx.x;
  const float4 v = ((const float4*)(in + row * 1024))[tid];
  float s = v.x + v.y + v.z + v.w;
#pragma unroll
  for (int o = 1; o < 64; o <<= 1) s += __shfl_xor(s, o);
  const int wid = tid >> 6, lane = tid & 63;
  if (lane == 0) red[wid] = s;
  __syncthreads();
  s = red[0] + red[1] + red[2] + red[3];
  const float mu = s * (1.f / 1024.f);
  const float d0 = v.x - mu, d1 = v.y - mu, d2 = v.z - mu, d3 = v.w - mu;
  float sq = d0 * d0 + d1 * d1 + d2 * d2 + d3 * d3;
  __syncthreads();
#pragma unroll
  for (int o = 1; o < 64; o <<= 1) sq += __shfl_xor(sq, o);
  if (lane == 0) red[wid] = sq;
  __syncthreads();
  sq = red[0] + red[1] + red[2] + red[3];
  const float inv = rsqrtf(sq * (1.f / 1024.f) + 1e-5f);
  const float4 gv = ((const float4*)(gam))[tid];
  const float4 bv = ((const float4*)(bet))[tid];
  float o0 = d0 * inv * gv.x + bv.x;
  float o1 = d1 * inv * gv.y + bv.y;
  float o2 = d2 * inv * gv.z + bv.z;
  float o3 = d3 * inv * gv.w + bv.w;
  if (addend) {
    const float4 a = ((const float4*)(addend + row * 1024))[tid];
    o0 += a.x; o1 += a.y; o2 += a.z; o3 += a.w;
  }
  if (outf)
    ((float4*)(outf + row * 1024))[tid] = make_float4(o0, o1, o2, o3);
  if (outb) {
    const uint32_t w0 = (uint32_t)f2bf(o0) | ((uint32_t)f2bf(o1) << 16);
    const uint32_t w1 = (uint32_t)f2bf(o2) | ((uint32_t)f2bf(o3) << 16);
    ((uint2*)(outb + row * 1024))[tid] = make_uint2(w0, w1);
  }
}

// ---------------------------------------------------------------- launch
extern "C" void kernel_launch(void* const* d_in, const int* in_sizes, int n_in,
                              void* d_out, int out_size, void* d_ws, size_t ws_size,
                              hipStream_t stream) {
  (void)in_sizes; (void)n_in; (void)out_size; (void)ws_size;
  const float* x     = (const float*)d_in[0];
  const float* y     = (const float*)d_in[1];
  const float* qkv_w = (const float*)d_in[3];
  const float* qkv_b = (const float*)d_in[4];
  const float* ao_w  = (const float*)d_in[5];
  const float* ao_b  = (const float*)d_in[6];
  const float* kv_w  = (const float*)d_in[7];
  const float* kv_b  = (const float*)d_in[8];
  const float* q_w   = (const float*)d_in[9];
  const float* q_b   = (const float*)d_in[10];
  const float* co_w  = (const float*)d_in[11];
  const float* co_b  = (const float*)d_in[12];
  const float* fc1_w = (const float*)d_in[13];
  const float* fc1_b = (const float*)d_in[14];
  const float* fc2_w = (const float*)d_in[15];
  const float* fc2_b = (const float*)d_in[16];
  const float* ln1_g = (const float*)d_in[17];
  const float* ln1_b = (const float*)d_in[18];
  const float* ln2_g = (const float*)d_in[19];
  const float* ln2_b = (const float*)d_in[20];
  const float* ln3_g = (const float*)d_in[21];
  const float* ln3_b = (const float*)d_in[22];

  char* ws = (char*)d_ws;
  size_t off = 0;
  auto alloc = [&](size_t bytes) {
    char* p = ws + off;
    off += (bytes + 255) & ~(size_t)255;
    return p;
  };
  uint16_t* xb     = (uint16_t*)alloc(4194304ull * 2);      // x bf16
  uint16_t* yb     = (uint16_t*)alloc(4194304ull * 2);      // y bf16
  uint16_t* wT_qkv = (uint16_t*)alloc(3072ull * 1024 * 2);
  uint16_t* wT_ao  = (uint16_t*)alloc(1024ull * 1024 * 2);
  uint16_t* wT_kv  = (uint16_t*)alloc(2048ull * 1024 * 2);
  uint16_t* wT_q   = (uint16_t*)alloc(1024ull * 1024 * 2);
  uint16_t* wT_co  = (uint16_t*)alloc(1024ull * 1024 * 2);
  uint16_t* wT_fc1 = (uint16_t*)alloc(2048ull * 1024 * 2);
  uint16_t* wT_fc2 = (uint16_t*)alloc(1024ull * 2048 * 2);
  uint16_t* QKV    = (uint16_t*)alloc(3ull * 4194304 * 2);  // Q|K|Vt, reused as CQ|CK|CVt
  uint16_t* SA     = (uint16_t*)alloc(4194304ull * 2);      // attn out merged (both attns)
  float*    YATT   = (float*)alloc(4194304ull * 4);         // y_att f32; later F1 (bf16)
  float*    TMP    = (float*)alloc(4194304ull * 4);         // pre-LN f32, reused 3x
  uint16_t* YCB    = (uint16_t*)alloc(4194304ull * 2);      // y_cross bf16

  const dim3 blk(256);

  prep<<<dim3(20480), blk, 0, stream>>>(x, y, xb, yb,
                                        qkv_w, wT_qkv, ao_w, wT_ao, kv_w, wT_kv,
                                        q_w, wT_q, co_w, wT_co, fc1_w, wT_fc1, fc2_w, wT_fc2);

  // self-attention branch
  gemm_bt<EP_QKV><<<dim3(24, 32), blk, 0, stream>>>(yb, wT_qkv, qkv_b, QKV, nullptr, 4096, 3072, 1024);
  attn_fused<true><<<dim3(16, 64), blk, 0, stream>>>(QKV, QKV + 4194304, QKV + 2 * 4194304, SA);
  gemm_bt<EP_RES_F32RES><<<dim3(8, 32), blk, 0, stream>>>(SA, wT_ao, ao_b, TMP, y, 4096, 1024, 1024);
  ln_kernel<<<dim3(4096), blk, 0, stream>>>(TMP, ln1_g, ln1_b, nullptr, YATT, nullptr);
  // cross-attention branch (kv from x, q from original y)
  gemm_bt<EP_SCKV><<<dim3(16, 32), blk, 0, stream>>>(xb, wT_kv, kv_b, QKV + 4194304, nullptr, 4096, 2048, 1024);
  gemm_bt<EP_Q><<<dim3(8, 32), blk, 0, stream>>>(yb, wT_q, q_b, QKV, nullptr, 4096, 1024, 1024);
  attn_fused<false><<<dim3(16, 64), blk, 0, stream>>>(QKV, QKV + 4194304, QKV + 2 * 4194304, SA);
  gemm_bt<EP_F32><<<dim3(8, 32), blk, 0, stream>>>(SA, wT_co, co_b, TMP, nullptr, 4096, 1024, 1024);
  ln_kernel<<<dim3(4096), blk, 0, stream>>>(TMP, ln2_g, ln2_b, YATT, nullptr, YCB);
  // feedforward
  gemm_bt<EP_RELU><<<dim3(16, 32), blk, 0, stream>>>(YCB, wT_fc1, fc1_b, (uint16_t*)YATT, nullptr, 4096, 2048, 1024);
  gemm_bt<EP_RES_B16RES><<<dim3(8, 32), blk, 0, stream>>>((const uint16_t*)YATT, wT_fc2, fc2_b, TMP, YCB, 4096, 1024, 2048);
  ln_kernel<<<dim3(4096), blk, 0, stream>>>(TMP, ln3_g, ln3_b, nullptr, (float*)d_out, nullptr);
}